// Round 3
// baseline (2792.238 us; speedup 1.0000x reference)
//
#include <hip/hip_runtime.h>
#include <math.h>

#define N 80
#define D 512
#define NV (N*N)        // 6400
#define NC (2*N-1)      // 159
#define NCOL (NC+1)     // 160
#define CQ 6241.000001  // (n1-1)*(n2-1) + ridge
#define CG_MAX 60

// ---- static device scratch (no dependence on ws_size) ----
__device__ double g_Mp0[N*N];
__device__ double g_m[2][N*D];
__device__ double g_lam[2][N];
__device__ double g_u[2][N*D];
__device__ double g_e[2][N*D];
__device__ double g_P[NV];          // p[v], v = i2*80 + i1
__device__ double g_Y[NCOL][NV];    // col0 = Q^-1 f ; cols 1..159 = Q^-1 A^T
__device__ double g_S[NC*NCOL];     // Schur complement, ld = 160
__device__ double g_rhs[NC];
__device__ double g_mu[NC];
__device__ double g_z[NV];

// Mp0 = data1 @ data2^T  (f64 accumulate)
__global__ void k_mp0(const float* __restrict__ d1, const float* __restrict__ d2) {
    int t = blockIdx.x*blockDim.x + threadIdx.x;
    if (t >= N*N) return;
    int i = t / N, j = t % N;
    double acc = 0.0;
    for (int c = 0; c < D; ++c) acc += (double)d1[i*D+c] * (double)d2[j*D+c];
    g_Mp0[i*N+j] = acc;
}

// m1 = Mp0 @ data2 ; m2 = Mp0^T @ data1
__global__ void k_m12(const float* __restrict__ d1, const float* __restrict__ d2) {
    int t = blockIdx.x*blockDim.x + threadIdx.x;
    if (t >= 2*N*D) return;
    if (t < N*D) {
        int i = t / D, k = t % D;
        double acc = 0.0;
        for (int j = 0; j < N; ++j) acc += g_Mp0[i*N+j] * (double)d2[j*D+k];
        g_m[0][t] = acc;
    } else {
        int r = t - N*D; int j = r / D, k = r % D;
        double acc = 0.0;
        for (int i = 0; i < N; ++i) acc += g_Mp0[i*N+j] * (double)d1[i*D+k];
        g_m[1][r] = acc;
    }
}

// lam = ||data_row|| / ||m_row||
__global__ void k_lam(const float* __restrict__ d1, const float* __restrict__ d2) {
    int t = blockIdx.x*blockDim.x + threadIdx.x;
    if (t >= 2*N) return;
    int g = t / N, row = t % N;
    const float* dd = g ? d2 : d1;
    double sd = 0.0, sm = 0.0;
    for (int c = 0; c < D; ++c) {
        double a = (double)dd[row*D+c]; sd += a*a;
        double m = g_m[g][row*D+c];     sm += m*m;
    }
    g_lam[g][row] = sqrt(sd) / sqrt(sm);
}

// u = data + lam * m
__global__ void k_u(const float* __restrict__ d1, const float* __restrict__ d2) {
    int t = blockIdx.x*blockDim.x + threadIdx.x;
    if (t >= 2*N*D) return;
    int g = t / (N*D), r = t % (N*D);
    int i = r / D;
    const float* dd = g ? d2 : d1;
    g_u[g][r] = (double)dd[r] + g_lam[g][i] * g_m[g][r];
}

// e = relu(u @ W^T + b)
__global__ void k_e(const float* __restrict__ W, const float* __restrict__ b) {
    int t = blockIdx.x*blockDim.x + threadIdx.x;
    if (t >= 2*N*D) return;
    int g = t / (N*D), r = t % (N*D);
    int i = r / D, k = r % D;
    double acc = (double)b[k];
    const double* u = g_u[g] + i*D;
    const float*  w = W + k*D;
    for (int c = 0; c < D; ++c) acc += u[c] * (double)w[c];
    g_e[g][r] = acc > 0.0 ? acc : 0.0;
}

// l2-normalize rows of e (eps 1e-12)
__global__ void k_enorm() {
    __shared__ double red[256];
    int bid = blockIdx.x;           // 0..159
    int g = bid / N, row = bid % N;
    double* e = g_e[g] + row*D;
    int tid = threadIdx.x;
    double s = 0.0;
    for (int c = tid; c < D; c += 256) { double v = e[c]; s += v*v; }
    red[tid] = s; __syncthreads();
    for (int o = 128; o > 0; o >>= 1) { if (tid < o) red[tid] += red[tid+o]; __syncthreads(); }
    double nrm = sqrt(red[0]); if (nrm < 1e-12) nrm = 1e-12;
    double inv = 1.0 / nrm;
    for (int c = tid; c < D; c += 256) e[c] *= inv;
}

// P[v] = e1n[i1] . e2n[i2]
__global__ void k_p() {
    int v = blockIdx.x*blockDim.x + threadIdx.x;
    if (v >= NV) return;
    int i1 = v % N, i2 = v / N;
    const double* a = g_e[0] + i1*D;
    const double* c2 = g_e[1] + i2*D;
    double acc = 0.0;
    for (int c = 0; c < D; ++c) acc += a[c] * c2[c];
    g_P[v] = acc;
}

// 160 independent CG solves of Q x = b  (one block per RHS)
// Q x = CQ*x - 0.5*(p .* (Kx) + K(p .* x)),  (Kx)[v] = T - R[i1] - C[i2] + x[v]
__global__ void __launch_bounds__(256,1) k_cg() {
    __shared__ double sd[NV];                    // search direction d
    __shared__ double sRd[N], sCd[N], sRy[N], sCy[N];
    __shared__ double red[256];
    __shared__ double sc[2];
    int k = blockIdx.x;
    int tid = threadIdx.x;
    double x[25], r[25], ploc[25];

    #pragma unroll
    for (int j = 0; j < 25; ++j) { int v = tid + 256*j; ploc[j] = g_P[v]; }

    double rs = 0.0;
    #pragma unroll
    for (int j = 0; j < 25; ++j) {
        int v = tid + 256*j;
        int i1 = v % N, i2 = v / N;
        double bv;
        if (k == 0)      bv = ploc[j];
        else if (k <= N) bv = (i1 == k-1)   ? 1.0 : 0.0;
        else             bv = (i2 == k-1-N) ? 1.0 : 0.0;
        x[j] = 0.0; r[j] = bv; sd[v] = bv;
        rs += bv*bv;
    }
    red[tid] = rs; __syncthreads();
    for (int o = 128; o > 0; o >>= 1) { if (tid < o) red[tid] += red[tid+o]; __syncthreads(); }
    rs = red[0];
    double rs0 = rs;
    __syncthreads();

    for (int it = 0; it < CG_MAX && rs > 1e-26*rs0; ++it) {
        // row/col/total sums of d and y = p.*d
        if (tid < N) {            // C[i2=tid]: contiguous
            double cd = 0.0, cy = 0.0;
            const double* dd = sd + tid*N;
            const double* pp = g_P + tid*N;
            for (int i1 = 0; i1 < N; ++i1) { double dv = dd[i1]; cd += dv; cy += pp[i1]*dv; }
            sCd[tid] = cd; sCy[tid] = cy;
        } else if (tid < 2*N) {   // R[i1]: stride N
            int i1 = tid - N; double rd = 0.0, ry = 0.0;
            for (int i2 = 0; i2 < N; ++i2) { double dv = sd[i2*N+i1]; rd += dv; ry += g_P[i2*N+i1]*dv; }
            sRd[i1] = rd; sRy[i1] = ry;
        }
        __syncthreads();
        if (tid == 0) { double s = 0.0; for (int i = 0; i < N; ++i) s += sCd[i]; sc[0] = s; }
        if (tid == 1) { double s = 0.0; for (int i = 0; i < N; ++i) s += sCy[i]; sc[1] = s; }
        __syncthreads();
        double Td = sc[0], Ty = sc[1];

        // d . Qd
        double dq = 0.0;
        #pragma unroll
        for (int j = 0; j < 25; ++j) {
            int v = tid + 256*j; int i1 = v % N, i2 = v / N;
            double dv = sd[v], pv = ploc[j];
            double Kd = Td - sRd[i1] - sCd[i2] + dv;
            double Ky = Ty - sRy[i1] - sCy[i2] + pv*dv;
            double q  = CQ*dv - 0.5*(pv*Kd + Ky);
            dq += dv*q;
        }
        red[tid] = dq; __syncthreads();
        for (int o = 128; o > 0; o >>= 1) { if (tid < o) red[tid] += red[tid+o]; __syncthreads(); }
        double alpha = rs / red[0];
        __syncthreads();

        // x += a d ; r -= a q (q recomputed) ; rsn
        double rsn = 0.0;
        #pragma unroll
        for (int j = 0; j < 25; ++j) {
            int v = tid + 256*j; int i1 = v % N, i2 = v / N;
            double dv = sd[v], pv = ploc[j];
            double Kd = Td - sRd[i1] - sCd[i2] + dv;
            double Ky = Ty - sRy[i1] - sCy[i2] + pv*dv;
            double q  = CQ*dv - 0.5*(pv*Kd + Ky);
            x[j] += alpha*dv;
            r[j] -= alpha*q;
            rsn += r[j]*r[j];
        }
        red[tid] = rsn; __syncthreads();
        for (int o = 128; o > 0; o >>= 1) { if (tid < o) red[tid] += red[tid+o]; __syncthreads(); }
        rsn = red[0];
        double beta = rsn / rs;
        rs = rsn;
        __syncthreads();

        #pragma unroll
        for (int j = 0; j < 25; ++j) { int v = tid + 256*j; sd[v] = r[j] + beta*sd[v]; }
        __syncthreads();
    }
    #pragma unroll
    for (int j = 0; j < 25; ++j) { int v = tid + 256*j; g_Y[k][v] = x[j]; }
}

// S = A Y[1:],  rhs = A y0 - 1
__global__ void k_schur() {
    int t = blockIdx.x*blockDim.x + threadIdx.x;
    if (t >= NC*NCOL) return;
    int rr = t / NCOL, kk = t % NCOL;
    const double* Y = g_Y[kk];
    double s = 0.0;
    if (rr < N) { for (int i2 = 0; i2 < N; ++i2) s += Y[i2*N+rr]; }
    else        { int q = rr - N; for (int i1 = 0; i1 < N; ++i1) s += Y[q*N+i1]; }
    if (kk == 0) g_rhs[rr] = s - 1.0;
    else         g_S[rr*NCOL + (kk-1)] = s;
}

// single-block SPD Cholesky of S (in global, lower triangle) + 2 triangular solves
__global__ void __launch_bounds__(256,1) k_chol() {
    __shared__ double colk[NC];
    __shared__ double yv[NC];
    __shared__ double red[256];
    int tid = threadIdx.x;
    for (int k = 0; k < NC; ++k) {
        if (tid == 0) g_S[k*NCOL+k] = sqrt(g_S[k*NCOL+k]);
        __syncthreads();
        double lkk = g_S[k*NCOL+k];
        for (int i = k+1+tid; i < NC; i += 256) {
            double v = g_S[i*NCOL+k] / lkk;
            g_S[i*NCOL+k] = v; colk[i] = v;
        }
        __syncthreads();
        for (int i = k+1+tid; i < NC; i += 256) {
            double lik = colk[i];
            for (int j = k+1; j <= i; ++j) g_S[i*NCOL+j] -= lik * colk[j];
        }
        __syncthreads();
    }
    // forward: L y = rhs
    for (int i = 0; i < NC; ++i) {
        double part = 0.0;
        for (int j = tid; j < i; j += 256) part += g_S[i*NCOL+j] * yv[j];
        red[tid] = part; __syncthreads();
        for (int o = 128; o > 0; o >>= 1) { if (tid < o) red[tid] += red[tid+o]; __syncthreads(); }
        if (tid == 0) yv[i] = (g_rhs[i] - red[0]) / g_S[i*NCOL+i];
        __syncthreads();
    }
    // backward: L^T mu = y
    for (int i = NC-1; i >= 0; --i) {
        double part = 0.0;
        for (int j = i+1+tid; j < NC; j += 256) part += g_S[j*NCOL+i] * yv[j];
        red[tid] = part; __syncthreads();
        for (int o = 128; o > 0; o >>= 1) { if (tid < o) red[tid] += red[tid+o]; __syncthreads(); }
        if (tid == 0) yv[i] = (yv[i] - red[0]) / g_S[i*NCOL+i];
        __syncthreads();
    }
    for (int i = tid; i < NC; i += 256) g_mu[i] = yv[i];
}

// z = y0 - Y[1:] mu
__global__ void k_z() {
    __shared__ double smu[NC];
    int tid = threadIdx.x;
    for (int i = tid; i < NC; i += 256) smu[i] = g_mu[i];
    __syncthreads();
    int v = blockIdx.x*256 + tid;
    if (v < NV) {
        double acc = g_Y[0][v];
        for (int q = 0; q < NC; ++q) acc -= g_Y[q+1][v] * smu[q];
        g_z[v] = acc;
    }
}

// s = clip(z) ; out = softmax(1000*s, axis=i2)
__global__ void k_out(float* __restrict__ out) {
    __shared__ double red[128];
    int i1 = blockIdx.x, tid = threadIdx.x;
    double sv = 0.0, val = -1e300;
    if (tid < N) {
        sv = g_z[tid*N + i1];
        sv = sv < 0.0 ? 0.0 : (sv > 1.0 ? 1.0 : sv);
        val = sv;
    }
    red[tid] = val; __syncthreads();
    for (int o = 64; o > 0; o >>= 1) { if (tid < o) red[tid] = fmax(red[tid], red[tid+o]); __syncthreads(); }
    double m = red[0];
    __syncthreads();
    double w = 0.0;
    if (tid < N) w = exp(1000.0*(sv - m));
    red[tid] = w; __syncthreads();
    for (int o = 64; o > 0; o >>= 1) { if (tid < o) red[tid] += red[tid+o]; __syncthreads(); }
    double tot = red[0];
    if (tid < N) out[i1*N + tid] = (float)(w / tot);
}

extern "C" void kernel_launch(void* const* d_in, const int* in_sizes, int n_in,
                              void* d_out, int out_size, void* d_ws, size_t ws_size,
                              hipStream_t stream) {
    const float* d1 = (const float*)d_in[0];
    const float* d2 = (const float*)d_in[1];
    const float* W  = (const float*)d_in[2];
    const float* b  = (const float*)d_in[3];
    float* out = (float*)d_out;

    k_mp0  <<<dim3(25),  dim3(256), 0, stream>>>(d1, d2);
    k_m12  <<<dim3(320), dim3(256), 0, stream>>>(d1, d2);
    k_lam  <<<dim3(1),   dim3(256), 0, stream>>>(d1, d2);
    k_u    <<<dim3(320), dim3(256), 0, stream>>>(d1, d2);
    k_e    <<<dim3(320), dim3(256), 0, stream>>>(W, b);
    k_enorm<<<dim3(160), dim3(256), 0, stream>>>();
    k_p    <<<dim3(25),  dim3(256), 0, stream>>>();
    k_cg   <<<dim3(160), dim3(256), 0, stream>>>();
    k_schur<<<dim3(100), dim3(256), 0, stream>>>();
    k_chol <<<dim3(1),   dim3(256), 0, stream>>>();
    k_z    <<<dim3(25),  dim3(256), 0, stream>>>();
    k_out  <<<dim3(N),   dim3(128), 0, stream>>>(out);
}

// Round 4
// 850.162 us; speedup vs baseline: 3.2844x; 3.2844x over previous
//
#include <hip/hip_runtime.h>
#include <math.h>

#define N 80
#define D 512
#define NV (N*N)        // 6400
#define NC (2*N-1)      // 159
#define NCOL (NC+1)     // 160
#define CQ 6241.000001  // (n1-1)*(n2-1) + ridge
#define CG_MAX 60
#define TRI (NC*(NC+1)/2)   // 12720 packed lower-triangle elements

// ---- static device scratch (no dependence on ws_size) ----
__device__ double g_Mp0[N*N];
__device__ double g_m[2][N*D];
__device__ double g_lam[2][N];
__device__ double g_u[2][N*D];
__device__ double g_e[2][N*D];
__device__ double g_P[NV];          // p[v], v = i2*80 + i1
__device__ double g_Y[NCOL][NV];    // col0 = Q^-1 f ; cols 1..159 = Q^-1 A^T
__device__ double g_S[NC*NCOL];     // Schur complement, ld = 160
__device__ double g_rhs[NC];
__device__ double g_mu[NC];
__device__ double g_z[NV];

// Mp0 = data1 @ data2^T  (f64 accumulate)
__global__ void k_mp0(const float* __restrict__ d1, const float* __restrict__ d2) {
    int t = blockIdx.x*blockDim.x + threadIdx.x;
    if (t >= N*N) return;
    int i = t / N, j = t % N;
    double acc = 0.0;
    for (int c = 0; c < D; ++c) acc += (double)d1[i*D+c] * (double)d2[j*D+c];
    g_Mp0[i*N+j] = acc;
}

// m1 = Mp0 @ data2 ; m2 = Mp0^T @ data1
__global__ void k_m12(const float* __restrict__ d1, const float* __restrict__ d2) {
    int t = blockIdx.x*blockDim.x + threadIdx.x;
    if (t >= 2*N*D) return;
    if (t < N*D) {
        int i = t / D, k = t % D;
        double acc = 0.0;
        for (int j = 0; j < N; ++j) acc += g_Mp0[i*N+j] * (double)d2[j*D+k];
        g_m[0][t] = acc;
    } else {
        int r = t - N*D; int j = r / D, k = r % D;
        double acc = 0.0;
        for (int i = 0; i < N; ++i) acc += g_Mp0[i*N+j] * (double)d1[i*D+k];
        g_m[1][r] = acc;
    }
}

// lam = ||data_row|| / ||m_row||
__global__ void k_lam(const float* __restrict__ d1, const float* __restrict__ d2) {
    int t = blockIdx.x*blockDim.x + threadIdx.x;
    if (t >= 2*N) return;
    int g = t / N, row = t % N;
    const float* dd = g ? d2 : d1;
    double sd = 0.0, sm = 0.0;
    for (int c = 0; c < D; ++c) {
        double a = (double)dd[row*D+c]; sd += a*a;
        double m = g_m[g][row*D+c];     sm += m*m;
    }
    g_lam[g][row] = sqrt(sd) / sqrt(sm);
}

// u = data + lam * m
__global__ void k_u(const float* __restrict__ d1, const float* __restrict__ d2) {
    int t = blockIdx.x*blockDim.x + threadIdx.x;
    if (t >= 2*N*D) return;
    int g = t / (N*D), r = t % (N*D);
    int i = r / D;
    const float* dd = g ? d2 : d1;
    g_u[g][r] = (double)dd[r] + g_lam[g][i] * g_m[g][r];
}

// e = relu(u @ W^T + b)
__global__ void k_e(const float* __restrict__ W, const float* __restrict__ b) {
    int t = blockIdx.x*blockDim.x + threadIdx.x;
    if (t >= 2*N*D) return;
    int g = t / (N*D), r = t % (N*D);
    int i = r / D, k = r % D;
    double acc = (double)b[k];
    const double* u = g_u[g] + i*D;
    const float*  w = W + k*D;
    for (int c = 0; c < D; ++c) acc += u[c] * (double)w[c];
    g_e[g][r] = acc > 0.0 ? acc : 0.0;
}

// l2-normalize rows of e (eps 1e-12)
__global__ void k_enorm() {
    __shared__ double red[256];
    int bid = blockIdx.x;           // 0..159
    int g = bid / N, row = bid % N;
    double* e = g_e[g] + row*D;
    int tid = threadIdx.x;
    double s = 0.0;
    for (int c = tid; c < D; c += 256) { double v = e[c]; s += v*v; }
    red[tid] = s; __syncthreads();
    for (int o = 128; o > 0; o >>= 1) { if (tid < o) red[tid] += red[tid+o]; __syncthreads(); }
    double nrm = sqrt(red[0]); if (nrm < 1e-12) nrm = 1e-12;
    double inv = 1.0 / nrm;
    for (int c = tid; c < D; c += 256) e[c] *= inv;
}

// P[v] = e1n[i1] . e2n[i2]
__global__ void k_p() {
    int v = blockIdx.x*blockDim.x + threadIdx.x;
    if (v >= NV) return;
    int i1 = v % N, i2 = v / N;
    const double* a = g_e[0] + i1*D;
    const double* c2 = g_e[1] + i2*D;
    double acc = 0.0;
    for (int c = 0; c < D; ++c) acc += a[c] * c2[c];
    g_P[v] = acc;
}

// 160 independent CG solves of Q x = b  (one block per RHS)
// Q x = CQ*x - 0.5*(p .* (Kx) + K(p .* x)),  (Kx)[v] = T - R[i1] - C[i2] + x[v]
__global__ void __launch_bounds__(256,1) k_cg() {
    __shared__ double sd[NV];                    // search direction d
    __shared__ double sRd[N], sCd[N], sRy[N], sCy[N];
    __shared__ double red[256];
    __shared__ double sc[2];
    int k = blockIdx.x;
    int tid = threadIdx.x;
    double x[25], r[25], ploc[25];

    #pragma unroll
    for (int j = 0; j < 25; ++j) { int v = tid + 256*j; ploc[j] = g_P[v]; }

    double rs = 0.0;
    #pragma unroll
    for (int j = 0; j < 25; ++j) {
        int v = tid + 256*j;
        int i1 = v % N, i2 = v / N;
        double bv;
        if (k == 0)      bv = ploc[j];
        else if (k <= N) bv = (i1 == k-1)   ? 1.0 : 0.0;
        else             bv = (i2 == k-1-N) ? 1.0 : 0.0;
        x[j] = 0.0; r[j] = bv; sd[v] = bv;
        rs += bv*bv;
    }
    red[tid] = rs; __syncthreads();
    for (int o = 128; o > 0; o >>= 1) { if (tid < o) red[tid] += red[tid+o]; __syncthreads(); }
    rs = red[0];
    double rs0 = rs;
    __syncthreads();

    for (int it = 0; it < CG_MAX && rs > 1e-26*rs0; ++it) {
        // row/col/total sums of d and y = p.*d
        if (tid < N) {            // C[i2=tid]: contiguous
            double cd = 0.0, cy = 0.0;
            const double* dd = sd + tid*N;
            const double* pp = g_P + tid*N;
            for (int i1 = 0; i1 < N; ++i1) { double dv = dd[i1]; cd += dv; cy += pp[i1]*dv; }
            sCd[tid] = cd; sCy[tid] = cy;
        } else if (tid < 2*N) {   // R[i1]: stride N
            int i1 = tid - N; double rd = 0.0, ry = 0.0;
            for (int i2 = 0; i2 < N; ++i2) { double dv = sd[i2*N+i1]; rd += dv; ry += g_P[i2*N+i1]*dv; }
            sRd[i1] = rd; sRy[i1] = ry;
        }
        __syncthreads();
        if (tid == 0) { double s = 0.0; for (int i = 0; i < N; ++i) s += sCd[i]; sc[0] = s; }
        if (tid == 1) { double s = 0.0; for (int i = 0; i < N; ++i) s += sCy[i]; sc[1] = s; }
        __syncthreads();
        double Td = sc[0], Ty = sc[1];

        // d . Qd
        double dq = 0.0;
        #pragma unroll
        for (int j = 0; j < 25; ++j) {
            int v = tid + 256*j; int i1 = v % N, i2 = v / N;
            double dv = sd[v], pv = ploc[j];
            double Kd = Td - sRd[i1] - sCd[i2] + dv;
            double Ky = Ty - sRy[i1] - sCy[i2] + pv*dv;
            double q  = CQ*dv - 0.5*(pv*Kd + Ky);
            dq += dv*q;
        }
        red[tid] = dq; __syncthreads();
        for (int o = 128; o > 0; o >>= 1) { if (tid < o) red[tid] += red[tid+o]; __syncthreads(); }
        double alpha = rs / red[0];
        __syncthreads();

        // x += a d ; r -= a q (q recomputed) ; rsn
        double rsn = 0.0;
        #pragma unroll
        for (int j = 0; j < 25; ++j) {
            int v = tid + 256*j; int i1 = v % N, i2 = v / N;
            double dv = sd[v], pv = ploc[j];
            double Kd = Td - sRd[i1] - sCd[i2] + dv;
            double Ky = Ty - sRy[i1] - sCy[i2] + pv*dv;
            double q  = CQ*dv - 0.5*(pv*Kd + Ky);
            x[j] += alpha*dv;
            r[j] -= alpha*q;
            rsn += r[j]*r[j];
        }
        red[tid] = rsn; __syncthreads();
        for (int o = 128; o > 0; o >>= 1) { if (tid < o) red[tid] += red[tid+o]; __syncthreads(); }
        rsn = red[0];
        double beta = rsn / rs;
        rs = rsn;
        __syncthreads();

        #pragma unroll
        for (int j = 0; j < 25; ++j) { int v = tid + 256*j; sd[v] = r[j] + beta*sd[v]; }
        __syncthreads();
    }
    #pragma unroll
    for (int j = 0; j < 25; ++j) { int v = tid + 256*j; g_Y[k][v] = x[j]; }
}

// S = A Y[1:],  rhs = A y0 - 1
__global__ void k_schur() {
    int t = blockIdx.x*blockDim.x + threadIdx.x;
    if (t >= NC*NCOL) return;
    int rr = t / NCOL, kk = t % NCOL;
    const double* Y = g_Y[kk];
    double s = 0.0;
    if (rr < N) { for (int i2 = 0; i2 < N; ++i2) s += Y[i2*N+rr]; }
    else        { int q = rr - N; for (int i1 = 0; i1 < N; ++i1) s += Y[q*N+i1]; }
    if (kk == 0) g_rhs[rr] = s - 1.0;
    else         g_S[rr*NCOL + (kk-1)] = s;
}

// single-block SPD Cholesky, entirely in LDS (packed lower triangle),
// + column-oriented triangular solves (no reductions).
__global__ void __launch_bounds__(256,1) k_chol() {
    __shared__ double L[TRI];      // packed: row i starts at i*(i+1)/2
    __shared__ double colk[NC];
    __shared__ double yv[NC];
    int tid = threadIdx.x;

    // load lower triangle of S into LDS
    for (int i = 0; i < NC; ++i) {
        int off = i*(i+1)/2;
        for (int j = tid; j <= i; j += 256) L[off+j] = g_S[i*NCOL+j];
    }
    __syncthreads();

    // right-looking Cholesky
    for (int k = 0; k < NC; ++k) {
        int offk = k*(k+1)/2;
        if (tid == 0) {
            double v = sqrt(L[offk+k]);
            L[offk+k] = v; colk[k] = v;
        }
        __syncthreads();
        double inv = 1.0 / colk[k];
        for (int i = k+1+tid; i < NC; i += 256) {
            double v = L[i*(i+1)/2 + k] * inv;
            L[i*(i+1)/2 + k] = v;
            colk[i] = v;
        }
        __syncthreads();
        // rank-1 update: L[i][j] -= colk[i]*colk[j], k < j <= i
        // two threads per row, alternating j
        int half = tid & 1;
        for (int i = k+1 + (tid>>1); i < NC; i += 128) {
            int off = i*(i+1)/2;
            double ci = colk[i];
            for (int j = k+1+half; j <= i; j += 2) L[off+j] -= ci*colk[j];
        }
        __syncthreads();
    }

    // forward solve L y = rhs (column-oriented: parallel updates, no reduction)
    for (int i = tid; i < NC; i += 256) yv[i] = g_rhs[i];
    __syncthreads();
    for (int i = 0; i < NC; ++i) {
        if (tid == 0) yv[i] /= L[i*(i+1)/2 + i];
        __syncthreads();
        double yi = yv[i];
        for (int j = i+1+tid; j < NC; j += 256) yv[j] -= L[j*(j+1)/2 + i] * yi;
        __syncthreads();
    }
    // backward solve L^T mu = y (row i of L is contiguous)
    for (int i = NC-1; i >= 0; --i) {
        if (tid == 0) yv[i] /= L[i*(i+1)/2 + i];
        __syncthreads();
        double xi = yv[i];
        int off = i*(i+1)/2;
        for (int j = tid; j < i; j += 256) yv[j] -= L[off+j] * xi;
        __syncthreads();
    }
    for (int i = tid; i < NC; i += 256) g_mu[i] = yv[i];
}

// z = y0 - Y[1:] mu
__global__ void k_z() {
    __shared__ double smu[NC];
    int tid = threadIdx.x;
    for (int i = tid; i < NC; i += 256) smu[i] = g_mu[i];
    __syncthreads();
    int v = blockIdx.x*256 + tid;
    if (v < NV) {
        double acc = g_Y[0][v];
        for (int q = 0; q < NC; ++q) acc -= g_Y[q+1][v] * smu[q];
        g_z[v] = acc;
    }
}

// s = clip(z) ; out = softmax(1000*s, axis=i2)
__global__ void k_out(float* __restrict__ out) {
    __shared__ double red[128];
    int i1 = blockIdx.x, tid = threadIdx.x;
    double sv = 0.0, val = -1e300;
    if (tid < N) {
        sv = g_z[tid*N + i1];
        sv = sv < 0.0 ? 0.0 : (sv > 1.0 ? 1.0 : sv);
        val = sv;
    }
    red[tid] = val; __syncthreads();
    for (int o = 64; o > 0; o >>= 1) { if (tid < o) red[tid] = fmax(red[tid], red[tid+o]); __syncthreads(); }
    double m = red[0];
    __syncthreads();
    double w = 0.0;
    if (tid < N) w = exp(1000.0*(sv - m));
    red[tid] = w; __syncthreads();
    for (int o = 64; o > 0; o >>= 1) { if (tid < o) red[tid] += red[tid+o]; __syncthreads(); }
    double tot = red[0];
    if (tid < N) out[i1*N + tid] = (float)(w / tot);
}

extern "C" void kernel_launch(void* const* d_in, const int* in_sizes, int n_in,
                              void* d_out, int out_size, void* d_ws, size_t ws_size,
                              hipStream_t stream) {
    const float* d1 = (const float*)d_in[0];
    const float* d2 = (const float*)d_in[1];
    const float* W  = (const float*)d_in[2];
    const float* b  = (const float*)d_in[3];
    float* out = (float*)d_out;

    k_mp0  <<<dim3(25),  dim3(256), 0, stream>>>(d1, d2);
    k_m12  <<<dim3(320), dim3(256), 0, stream>>>(d1, d2);
    k_lam  <<<dim3(1),   dim3(256), 0, stream>>>(d1, d2);
    k_u    <<<dim3(320), dim3(256), 0, stream>>>(d1, d2);
    k_e    <<<dim3(320), dim3(256), 0, stream>>>(W, b);
    k_enorm<<<dim3(160), dim3(256), 0, stream>>>();
    k_p    <<<dim3(25),  dim3(256), 0, stream>>>();
    k_cg   <<<dim3(160), dim3(256), 0, stream>>>();
    k_schur<<<dim3(100), dim3(256), 0, stream>>>();
    k_chol <<<dim3(1),   dim3(256), 0, stream>>>();
    k_z    <<<dim3(25),  dim3(256), 0, stream>>>();
    k_out  <<<dim3(N),   dim3(128), 0, stream>>>(out);
}

// Round 5
// 241.410 us; speedup vs baseline: 11.5664x; 3.5216x over previous
//
#include <hip/hip_runtime.h>
#include <math.h>

#define N 80
#define D 512
#define NV (N*N)        // 6400
#define CQ 6241.000001  // (n1-1)*(n2-1) + ridge
#define CG_MAX 120

// ---- static device scratch ----
__device__ double g_Mp0[N*N];
__device__ double g_m[2][N*D];
__device__ double g_lam[2][N];
__device__ double g_u[2][N*D];
__device__ double g_e[2][N*D];
__device__ double g_P[NV];          // p[v], v = i2*80 + i1  (== Mpp == QP linear term)
__device__ double g_z[NV];

// Mp0 = data1 @ data2^T  (f64 accumulate)
__global__ void k_mp0(const float* __restrict__ d1, const float* __restrict__ d2) {
    int t = blockIdx.x*blockDim.x + threadIdx.x;
    if (t >= N*N) return;
    int i = t / N, j = t % N;
    double acc = 0.0;
    for (int c = 0; c < D; ++c) acc += (double)d1[i*D+c] * (double)d2[j*D+c];
    g_Mp0[i*N+j] = acc;
}

// m1 = Mp0 @ data2 ; m2 = Mp0^T @ data1
__global__ void k_m12(const float* __restrict__ d1, const float* __restrict__ d2) {
    int t = blockIdx.x*blockDim.x + threadIdx.x;
    if (t >= 2*N*D) return;
    if (t < N*D) {
        int i = t / D, k = t % D;
        double acc = 0.0;
        for (int j = 0; j < N; ++j) acc += g_Mp0[i*N+j] * (double)d2[j*D+k];
        g_m[0][t] = acc;
    } else {
        int r = t - N*D; int j = r / D, k = r % D;
        double acc = 0.0;
        for (int i = 0; i < N; ++i) acc += g_Mp0[i*N+j] * (double)d1[i*D+k];
        g_m[1][r] = acc;
    }
}

// lam = ||data_row|| / ||m_row||
__global__ void k_lam(const float* __restrict__ d1, const float* __restrict__ d2) {
    int t = blockIdx.x*blockDim.x + threadIdx.x;
    if (t >= 2*N) return;
    int g = t / N, row = t % N;
    const float* dd = g ? d2 : d1;
    double sd = 0.0, sm = 0.0;
    for (int c = 0; c < D; ++c) {
        double a = (double)dd[row*D+c]; sd += a*a;
        double m = g_m[g][row*D+c];     sm += m*m;
    }
    g_lam[g][row] = sqrt(sd) / sqrt(sm);
}

// u = data + lam * m
__global__ void k_u(const float* __restrict__ d1, const float* __restrict__ d2) {
    int t = blockIdx.x*blockDim.x + threadIdx.x;
    if (t >= 2*N*D) return;
    int g = t / (N*D), r = t % (N*D);
    int i = r / D;
    const float* dd = g ? d2 : d1;
    g_u[g][r] = (double)dd[r] + g_lam[g][i] * g_m[g][r];
}

// e = relu(u @ W^T + b)
__global__ void k_e(const float* __restrict__ W, const float* __restrict__ b) {
    int t = blockIdx.x*blockDim.x + threadIdx.x;
    if (t >= 2*N*D) return;
    int g = t / (N*D), r = t % (N*D);
    int i = r / D, k = r % D;
    double acc = (double)b[k];
    const double* u = g_u[g] + i*D;
    const float*  w = W + k*D;
    for (int c = 0; c < D; ++c) acc += u[c] * (double)w[c];
    g_e[g][r] = acc > 0.0 ? acc : 0.0;
}

// l2-normalize rows of e (eps 1e-12)
__global__ void k_enorm() {
    __shared__ double red[256];
    int bid = blockIdx.x;           // 0..159
    int g = bid / N, row = bid % N;
    double* e = g_e[g] + row*D;
    int tid = threadIdx.x;
    double s = 0.0;
    for (int c = tid; c < D; c += 256) { double v = e[c]; s += v*v; }
    red[tid] = s; __syncthreads();
    for (int o = 128; o > 0; o >>= 1) { if (tid < o) red[tid] += red[tid+o]; __syncthreads(); }
    double nrm = sqrt(red[0]); if (nrm < 1e-12) nrm = 1e-12;
    double inv = 1.0 / nrm;
    for (int c = tid; c < D; c += 256) e[c] *= inv;
}

// P[v] = e1n[i1] . e2n[i2]
__global__ void k_p() {
    int v = blockIdx.x*blockDim.x + threadIdx.x;
    if (v >= NV) return;
    int i1 = v % N, i2 = v / N;
    const double* a = g_e[0] + i1*D;
    const double* c2 = g_e[1] + i2*D;
    double acc = 0.0;
    for (int c = 0; c < D; ++c) acc += a[c] * c2[c];
    g_P[v] = acc;
}

// 4-wave block reduction: shuffle within wave, combine via LDS
__device__ __forceinline__ double bredux(double v, double* red4, double* sc, int slot, int tid) {
    #pragma unroll
    for (int o = 32; o > 0; o >>= 1) v += __shfl_down(v, o, 64);
    if ((tid & 63) == 0) red4[tid >> 6] = v;
    __syncthreads();
    if (tid == 0) sc[slot] = red4[0] + red4[1] + red4[2] + red4[3];
    __syncthreads();
    return sc[slot];
}

// Projected CG on the doubly-stochastic constraint manifold.
//  z = z0 + w, z0 = 1/80 everywhere (feasible), w in null(A).
//  Solve P Q P w = P(p - Q z0), P = closed-form row/col/total centering.
//  Q x = CQ*x - 0.5*(p.*(Kx) + K(p.*x)),  (Kx)[v] = T - R[i1] - C[i2] + x[v]
__global__ void __launch_bounds__(256,1) k_pcg() {
    __shared__ double sd[NV];                 // search direction
    __shared__ double sq[NV];                 // Qd (raw, then projected)
    __shared__ double sRd[N], sCd[N], sRy[N], sCy[N];
    __shared__ double sRq[N], sCq[N];
    __shared__ double red4[4];
    __shared__ double sc[6];
    const double inv80 = 1.0/80.0, inv6400 = 1.0/6400.0, CHI = 1.0/80.0;
    int tid = threadIdx.x;
    double x[25], r[25], ploc[25];

    #pragma unroll
    for (int j = 0; j < 25; ++j) ploc[j] = g_P[tid + 256*j];

    // ---- phase 0a: row/col/total sums of p (into sRq/sCq temporarily) ----
    if (tid < N) {
        double cs = 0.0; const double* pp = g_P + tid*N;
        for (int i1 = 0; i1 < N; ++i1) cs += pp[i1];
        sCq[tid] = cs;
    } else if (tid < 2*N) {
        int i1 = tid - N; double rr = 0.0;
        for (int i2 = 0; i2 < N; ++i2) rr += g_P[i2*N + i1];
        sRq[i1] = rr;
    }
    __syncthreads();
    if (tid == 0) { double s = 0.0; for (int i = 0; i < N; ++i) s += sCq[i]; sc[0] = s; }
    __syncthreads();
    double Tp = sc[0];

    // ---- phase 0b: r0_raw = p - Q z0 into sq ----
    //  Qz0[v] = CHI*(CQ - 0.5*(6242*p[v] + Tp - Rp[i1] - Cp[i2]))
    #pragma unroll
    for (int j = 0; j < 25; ++j) {
        int v = tid + 256*j; int i1 = v % N, i2 = v / N;
        double q0 = CHI*(CQ - 0.5*(6242.0*ploc[j] + Tp - sRq[i1] - sCq[i2]));
        sq[v] = ploc[j] - q0;
    }
    __syncthreads();

    // ---- phase 0c: project r0 = P r0_raw ----
    if (tid < N) {
        double cs = 0.0; const double* dd = sq + tid*N;
        for (int i1 = 0; i1 < N; ++i1) cs += dd[i1];
        sCq[tid] = cs;
    } else if (tid < 2*N) {
        int i1 = tid - N; double rr = 0.0;
        for (int i2 = 0; i2 < N; ++i2) rr += sq[i2*N + i1];
        sRq[i1] = rr;
    }
    __syncthreads();
    if (tid == 0) { double s = 0.0; for (int i = 0; i < N; ++i) s += sCq[i]; sc[1] = s; }
    __syncthreads();
    double Tq = sc[1];
    double rsp = 0.0;
    #pragma unroll
    for (int j = 0; j < 25; ++j) {
        int v = tid + 256*j; int i1 = v % N, i2 = v / N;
        double rv = sq[v] - sRq[i1]*inv80 - sCq[i2]*inv80 + Tq*inv6400;
        r[j] = rv; x[j] = 0.0; sd[v] = rv;
        rsp += rv*rv;
    }
    double rs = bredux(rsp, red4, sc, 2, tid);
    double rs0 = rs;

    // ---- main PCG loop ----
    for (int it = 0; it < CG_MAX && rs > 1e-26*rs0; ++it) {
        // sums of d and y = p.*d
        if (tid < N) {
            double cd = 0.0, cy = 0.0;
            const double* dd = sd + tid*N;
            const double* pp = g_P + tid*N;
            for (int i1 = 0; i1 < N; ++i1) { double dv = dd[i1]; cd += dv; cy += pp[i1]*dv; }
            sCd[tid] = cd; sCy[tid] = cy;
        } else if (tid < 2*N) {
            int i1 = tid - N; double rd = 0.0, ry = 0.0;
            for (int i2 = 0; i2 < N; ++i2) { double dv = sd[i2*N+i1]; rd += dv; ry += g_P[i2*N+i1]*dv; }
            sRd[i1] = rd; sRy[i1] = ry;
        }
        __syncthreads();
        if (tid == 0) { double s = 0.0; for (int i = 0; i < N; ++i) s += sCd[i]; sc[0] = s; }
        if (tid == 1) { double s = 0.0; for (int i = 0; i < N; ++i) s += sCy[i]; sc[1] = s; }
        __syncthreads();
        double Td = sc[0], Ty = sc[1];

        // q_raw = Q d into sq
        #pragma unroll
        for (int j = 0; j < 25; ++j) {
            int v = tid + 256*j; int i1 = v % N, i2 = v / N;
            double dv = sd[v], pv = ploc[j];
            double Kd = Td - sRd[i1] - sCd[i2] + dv;
            double Ky = Ty - sRy[i1] - sCy[i2] + pv*dv;
            sq[v] = CQ*dv - 0.5*(pv*Kd + Ky);
        }
        __syncthreads();

        // sums of q_raw
        if (tid < N) {
            double cs = 0.0; const double* dd = sq + tid*N;
            for (int i1 = 0; i1 < N; ++i1) cs += dd[i1];
            sCq[tid] = cs;
        } else if (tid < 2*N) {
            int i1 = tid - N; double rr = 0.0;
            for (int i2 = 0; i2 < N; ++i2) rr += sq[i2*N + i1];
            sRq[i1] = rr;
        }
        __syncthreads();
        if (tid == 2) { double s = 0.0; for (int i = 0; i < N; ++i) s += sCq[i]; sc[2] = s; }
        __syncthreads();
        double Tqq = sc[2];

        // project q (store back), accumulate d.q
        double dqp = 0.0;
        #pragma unroll
        for (int j = 0; j < 25; ++j) {
            int v = tid + 256*j; int i1 = v % N, i2 = v / N;
            double qv = sq[v] - sRq[i1]*inv80 - sCq[i2]*inv80 + Tqq*inv6400;
            sq[v] = qv;
            dqp += sd[v]*qv;
        }
        double dq = bredux(dqp, red4, sc, 3, tid);
        double alpha = rs / dq;

        // x += a d ; r -= a q ; rsn
        double rsnp = 0.0;
        #pragma unroll
        for (int j = 0; j < 25; ++j) {
            int v = tid + 256*j;
            x[j] += alpha*sd[v];
            r[j] -= alpha*sq[v];
            rsnp += r[j]*r[j];
        }
        double rsn = bredux(rsnp, red4, sc, 4, tid);
        double beta = rsn / rs;
        rs = rsn;

        #pragma unroll
        for (int j = 0; j < 25; ++j) { int v = tid + 256*j; sd[v] = r[j] + beta*sd[v]; }
        __syncthreads();
    }

    #pragma unroll
    for (int j = 0; j < 25; ++j) { int v = tid + 256*j; g_z[v] = CHI + x[j]; }
}

// s = clip(z) ; out = softmax(1000*s, axis=i2)
__global__ void k_out(float* __restrict__ out) {
    __shared__ double red[128];
    int i1 = blockIdx.x, tid = threadIdx.x;
    double sv = 0.0, val = -1e300;
    if (tid < N) {
        sv = g_z[tid*N + i1];
        sv = sv < 0.0 ? 0.0 : (sv > 1.0 ? 1.0 : sv);
        val = sv;
    }
    red[tid] = val; __syncthreads();
    for (int o = 64; o > 0; o >>= 1) { if (tid < o) red[tid] = fmax(red[tid], red[tid+o]); __syncthreads(); }
    double m = red[0];
    __syncthreads();
    double w = 0.0;
    if (tid < N) w = exp(1000.0*(sv - m));
    red[tid] = w; __syncthreads();
    for (int o = 64; o > 0; o >>= 1) { if (tid < o) red[tid] += red[tid+o]; __syncthreads(); }
    double tot = red[0];
    if (tid < N) out[i1*N + tid] = (float)(w / tot);
}

extern "C" void kernel_launch(void* const* d_in, const int* in_sizes, int n_in,
                              void* d_out, int out_size, void* d_ws, size_t ws_size,
                              hipStream_t stream) {
    const float* d1 = (const float*)d_in[0];
    const float* d2 = (const float*)d_in[1];
    const float* W  = (const float*)d_in[2];
    const float* b  = (const float*)d_in[3];
    float* out = (float*)d_out;

    k_mp0  <<<dim3(25),  dim3(256), 0, stream>>>(d1, d2);
    k_m12  <<<dim3(320), dim3(256), 0, stream>>>(d1, d2);
    k_lam  <<<dim3(1),   dim3(256), 0, stream>>>(d1, d2);
    k_u    <<<dim3(320), dim3(256), 0, stream>>>(d1, d2);
    k_e    <<<dim3(320), dim3(256), 0, stream>>>(W, b);
    k_enorm<<<dim3(160), dim3(256), 0, stream>>>();
    k_p    <<<dim3(25),  dim3(256), 0, stream>>>();
    k_pcg  <<<dim3(1),   dim3(256), 0, stream>>>();
    k_out  <<<dim3(N),   dim3(128), 0, stream>>>(out);
}

// Round 6
// 140.193 us; speedup vs baseline: 19.9171x; 1.7220x over previous
//
#include <hip/hip_runtime.h>
#include <math.h>

#define N 80
#define D 512
#define NV (N*N)        // 6400
#define CQ 6241.000001  // (n1-1)*(n2-1) + ridge
#define CG_MAX 16

// ---- static device scratch ----
__device__ double g_Mp0[N*N];
__device__ double g_m[2][N*D];
__device__ double g_u[2][N*D];
__device__ double g_e[2][N*D];
__device__ double g_P[NV];          // p[v], v = i2*80 + i1
__device__ double g_z[NV];

// Mp0 = data1 @ data2^T  (f64 accumulate, float4 loads, 4 chains)
__global__ void k_mp0(const float* __restrict__ d1, const float* __restrict__ d2) {
    int t = blockIdx.x*blockDim.x + threadIdx.x;
    if (t >= N*N) return;
    int i = t / N, j = t % N;
    const float4* A = reinterpret_cast<const float4*>(d1 + (size_t)i*D);
    const float4* B = reinterpret_cast<const float4*>(d2 + (size_t)j*D);
    double a0=0,a1=0,a2=0,a3=0;
    for (int c = 0; c < D/4; ++c) {
        float4 x = A[c], y = B[c];
        a0 += (double)x.x*(double)y.x; a1 += (double)x.y*(double)y.y;
        a2 += (double)x.z*(double)y.z; a3 += (double)x.w*(double)y.w;
    }
    g_Mp0[i*N+j] = (a0+a1)+(a2+a3);
}

// m1 = Mp0 @ data2 ; m2 = Mp0^T @ data1   (2 chains)
__global__ void k_m12(const float* __restrict__ d1, const float* __restrict__ d2) {
    int t = blockIdx.x*blockDim.x + threadIdx.x;
    if (t >= 2*N*D) return;
    if (t < N*D) {
        int i = t / D, k = t % D;
        double a0=0,a1=0;
        for (int j = 0; j < N; j += 2) {
            a0 += g_Mp0[i*N+j]   * (double)d2[j*D+k];
            a1 += g_Mp0[i*N+j+1] * (double)d2[(j+1)*D+k];
        }
        g_m[0][t] = a0+a1;
    } else {
        int r = t - N*D; int j = r / D, k = r % D;
        double a0=0,a1=0;
        for (int i = 0; i < N; i += 2) {
            a0 += g_Mp0[i*N+j]     * (double)d1[i*D+k];
            a1 += g_Mp0[(i+1)*N+j] * (double)d1[(i+1)*D+k];
        }
        g_m[1][r] = a0+a1;
    }
}

// fused lam + u:  block per (g,row).  lam = ||data_row||/||m_row||; u = data + lam*m
__global__ void k_lamu(const float* __restrict__ d1, const float* __restrict__ d2) {
    __shared__ double red[512];
    int bid = blockIdx.x;          // 0..159
    int g = bid / N, row = bid % N;
    const float* dd = (g ? d2 : d1) + (size_t)row*D;
    const double* mm = g_m[g] + (size_t)row*D;
    int tid = threadIdx.x;
    double sd = 0.0, sm = 0.0;
    for (int c = tid; c < D; c += 256) {
        double a = (double)dd[c]; sd += a*a;
        double m = mm[c];         sm += m*m;
    }
    red[tid] = sd; red[256+tid] = sm; __syncthreads();
    for (int o = 128; o > 0; o >>= 1) {
        if (tid < o) { red[tid] += red[tid+o]; red[256+tid] += red[256+tid+o]; }
        __syncthreads();
    }
    double lam = sqrt(red[0]) / sqrt(red[256]);
    double* uu = g_u[g] + (size_t)row*D;
    for (int c = tid; c < D; c += 256) uu[c] = (double)dd[c] + lam*mm[c];
}

// fused e = l2norm_rows(relu(u @ W^T + b)) : block per (g,i), u-row in LDS,
// 2 outputs/thread, 4 accumulator chains each, float4 W loads.
__global__ void __launch_bounds__(256,1) k_e(const float* __restrict__ W, const float* __restrict__ b) {
    __shared__ double su[D];
    __shared__ double red[256];
    int bid = blockIdx.x;          // 0..159
    int g = bid / N, i = bid % N;
    int tid = threadIdx.x;
    const double* uu = g_u[g] + (size_t)i*D;
    su[tid] = uu[tid]; su[tid+256] = uu[tid+256];
    __syncthreads();

    double e0, e1;
    {
        int k = tid;
        const float4* Wr = reinterpret_cast<const float4*>(W + (size_t)k*D);
        double a0=0,a1=0,a2=0,a3=0;
        for (int c4 = 0; c4 < D/4; ++c4) {
            float4 w = Wr[c4];
            a0 += su[4*c4+0]*(double)w.x; a1 += su[4*c4+1]*(double)w.y;
            a2 += su[4*c4+2]*(double)w.z; a3 += su[4*c4+3]*(double)w.w;
        }
        double acc = (double)b[k] + (a0+a1)+(a2+a3);
        e0 = acc > 0.0 ? acc : 0.0;
    }
    {
        int k = tid + 256;
        const float4* Wr = reinterpret_cast<const float4*>(W + (size_t)k*D);
        double a0=0,a1=0,a2=0,a3=0;
        for (int c4 = 0; c4 < D/4; ++c4) {
            float4 w = Wr[c4];
            a0 += su[4*c4+0]*(double)w.x; a1 += su[4*c4+1]*(double)w.y;
            a2 += su[4*c4+2]*(double)w.z; a3 += su[4*c4+3]*(double)w.w;
        }
        double acc = (double)b[k] + (a0+a1)+(a2+a3);
        e1 = acc > 0.0 ? acc : 0.0;
    }
    red[tid] = e0*e0 + e1*e1; __syncthreads();
    for (int o = 128; o > 0; o >>= 1) { if (tid < o) red[tid] += red[tid+o]; __syncthreads(); }
    double nrm = sqrt(red[0]); if (nrm < 1e-12) nrm = 1e-12;
    double inv = 1.0 / nrm;
    double* ee = g_e[g] + (size_t)i*D;
    ee[tid] = e0*inv; ee[tid+256] = e1*inv;
}

// P[v] = e1n[i1] . e2n[i2]   (4 chains)
__global__ void k_p() {
    int v = blockIdx.x*blockDim.x + threadIdx.x;
    if (v >= NV) return;
    int i1 = v % N, i2 = v / N;
    const double* a = g_e[0] + (size_t)i1*D;
    const double* c2 = g_e[1] + (size_t)i2*D;
    double a0=0,a1=0,a2=0,a3=0;
    for (int c = 0; c < D; c += 4) {
        a0 += a[c]*c2[c];     a1 += a[c+1]*c2[c+1];
        a2 += a[c+2]*c2[c+2]; a3 += a[c+3]*c2[c+3];
    }
    g_P[v] = (a0+a1)+(a2+a3);
}

// 4-wave block reduction
__device__ __forceinline__ double bredux(double v, double* red4, double* sc, int slot, int tid) {
    #pragma unroll
    for (int o = 32; o > 0; o >>= 1) v += __shfl_down(v, o, 64);
    if ((tid & 63) == 0) red4[tid >> 6] = v;
    __syncthreads();
    if (tid == 0) sc[slot] = red4[0] + red4[1] + red4[2] + red4[3];
    __syncthreads();
    return sc[slot];
}

// Projected CG, reduced operator:
//   on null(A): PQPd = CQ*d - P(p.*d);   r0 = (6402/160) * P(p);  z = 1/80 + w.
__global__ void __launch_bounds__(256,1) k_pcg() {
    __shared__ double sd[NV];                 // search direction
    __shared__ double sq[NV];                 // y = p.*d, then q
    __shared__ double sRy[N], sCy[N];
    __shared__ double red4[4];
    __shared__ double sc[4];
    const double inv80 = 1.0/80.0, inv6400 = 1.0/6400.0, CHI = 1.0/80.0;
    int tid = threadIdx.x;
    double x[25], r[25], ploc[25];

    #pragma unroll
    for (int j = 0; j < 25; ++j) { int v = tid + 256*j; ploc[j] = g_P[v]; sq[v] = ploc[j]; }
    __syncthreads();

    // ---- setup: sums of p -> r0 = (6402/160) P(p) ----
    if (tid < N) {
        double cs = 0.0; const double* dd = sq + tid*N;
        for (int i1 = 0; i1 < N; ++i1) cs += dd[i1];
        sCy[tid] = cs;
    } else if (tid < 2*N) {
        int i1 = tid - N; double rr = 0.0;
        for (int i2 = 0; i2 < N; ++i2) rr += sq[i2*N + i1];
        sRy[i1] = rr;
    }
    __syncthreads();
    if (tid == 0) { double s = 0.0; for (int i = 0; i < N; ++i) s += sCy[i]; sc[0] = s; }
    __syncthreads();
    double Tp = sc[0];
    const double SCALE = 6402.0/160.0;
    double rsp = 0.0;
    #pragma unroll
    for (int j = 0; j < 25; ++j) {
        int v = tid + 256*j; int i1 = v % N, i2 = v / N;
        double rv = SCALE*(ploc[j] - sRy[i1]*inv80 - sCy[i2]*inv80 + Tp*inv6400);
        r[j] = rv; x[j] = 0.0; sd[v] = rv;
        rsp += rv*rv;
    }
    double rs = bredux(rsp, red4, sc, 2, tid);
    double rs0 = rs;

    // ---- main loop: q = CQ*d - P(p.*d) ----
    for (int it = 0; it < CG_MAX && rs > 1e-22*rs0; ++it) {
        #pragma unroll
        for (int j = 0; j < 25; ++j) { int v = tid + 256*j; sq[v] = ploc[j]*sd[v]; }
        __syncthreads();
        if (tid < N) {
            double cs = 0.0; const double* dd = sq + tid*N;
            for (int i1 = 0; i1 < N; ++i1) cs += dd[i1];
            sCy[tid] = cs;
        } else if (tid < 2*N) {
            int i1 = tid - N; double rr = 0.0;
            for (int i2 = 0; i2 < N; ++i2) rr += sq[i2*N + i1];
            sRy[i1] = rr;
        }
        __syncthreads();
        if (tid == 0) { double s = 0.0; for (int i = 0; i < N; ++i) s += sCy[i]; sc[1] = s; }
        __syncthreads();
        double Ty = sc[1];

        double dqp = 0.0;
        #pragma unroll
        for (int j = 0; j < 25; ++j) {
            int v = tid + 256*j; int i1 = v % N, i2 = v / N;
            double qv = CQ*sd[v] - (sq[v] - sRy[i1]*inv80 - sCy[i2]*inv80 + Ty*inv6400);
            sq[v] = qv;
            dqp += sd[v]*qv;
        }
        double dq = bredux(dqp, red4, sc, 3, tid);
        double alpha = rs / dq;

        double rsnp = 0.0;
        #pragma unroll
        for (int j = 0; j < 25; ++j) {
            int v = tid + 256*j;
            x[j] += alpha*sd[v];
            r[j] -= alpha*sq[v];
            rsnp += r[j]*r[j];
        }
        double rsn = bredux(rsnp, red4, sc, 2, tid);
        double beta = rsn / rs;
        rs = rsn;

        #pragma unroll
        for (int j = 0; j < 25; ++j) { int v = tid + 256*j; sd[v] = r[j] + beta*sd[v]; }
        __syncthreads();
    }

    #pragma unroll
    for (int j = 0; j < 25; ++j) { int v = tid + 256*j; g_z[v] = CHI + x[j]; }
}

// s = clip(z) ; out = softmax(1000*s, axis=i2)
__global__ void k_out(float* __restrict__ out) {
    __shared__ double red[128];
    int i1 = blockIdx.x, tid = threadIdx.x;
    double sv = 0.0, val = -1e300;
    if (tid < N) {
        sv = g_z[tid*N + i1];
        sv = sv < 0.0 ? 0.0 : (sv > 1.0 ? 1.0 : sv);
        val = sv;
    }
    red[tid] = val; __syncthreads();
    for (int o = 64; o > 0; o >>= 1) { if (tid < o) red[tid] = fmax(red[tid], red[tid+o]); __syncthreads(); }
    double m = red[0];
    __syncthreads();
    double w = 0.0;
    if (tid < N) w = exp(1000.0*(sv - m));
    red[tid] = w; __syncthreads();
    for (int o = 64; o > 0; o >>= 1) { if (tid < o) red[tid] += red[tid+o]; __syncthreads(); }
    double tot = red[0];
    if (tid < N) out[i1*N + tid] = (float)(w / tot);
}

extern "C" void kernel_launch(void* const* d_in, const int* in_sizes, int n_in,
                              void* d_out, int out_size, void* d_ws, size_t ws_size,
                              hipStream_t stream) {
    const float* d1 = (const float*)d_in[0];
    const float* d2 = (const float*)d_in[1];
    const float* W  = (const float*)d_in[2];
    const float* b  = (const float*)d_in[3];
    float* out = (float*)d_out;

    k_mp0 <<<dim3(25),  dim3(256), 0, stream>>>(d1, d2);
    k_m12 <<<dim3(320), dim3(256), 0, stream>>>(d1, d2);
    k_lamu<<<dim3(160), dim3(256), 0, stream>>>(d1, d2);
    k_e   <<<dim3(160), dim3(256), 0, stream>>>(W, b);
    k_p   <<<dim3(25),  dim3(256), 0, stream>>>();
    k_pcg <<<dim3(1),   dim3(256), 0, stream>>>();
    k_out <<<dim3(N),   dim3(128), 0, stream>>>(out);
}

// Round 8
// 106.388 us; speedup vs baseline: 26.2458x; 1.3177x over previous
//
#include <hip/hip_runtime.h>
#include <math.h>

#define N 80
#define D 512
#define NV (N*N)        // 6400
#define CQ 6241.000001  // (n1-1)*(n2-1) + ridge
#define CG_MAX 16

// ---- static device scratch ----
__device__ double g_Mp0[N*N];
__device__ double g_m[2][N*D];
__device__ double g_u[2][N*D];
__device__ double g_e[2][N*D];
__device__ double g_P[NV];          // p[v], v = i2*80 + i1
__device__ double g_z[NV];

// Mp0 = data1 @ data2^T ; 8 threads per output, 64 floats each (f64 accum)
__global__ void k_mp0(const float* __restrict__ d1, const float* __restrict__ d2) {
    int gidx = blockIdx.x*256 + threadIdx.x;      // 51200 threads
    int v = gidx >> 3, ch = gidx & 7;
    int i = v / N, j = v % N;
    const float4* A = reinterpret_cast<const float4*>(d1 + (size_t)i*D + ch*64);
    const float4* B = reinterpret_cast<const float4*>(d2 + (size_t)j*D + ch*64);
    double a0=0,a1=0,a2=0,a3=0;
    #pragma unroll
    for (int c = 0; c < 16; ++c) {
        float4 x = A[c], y = B[c];
        a0 += (double)x.x*(double)y.x; a1 += (double)x.y*(double)y.y;
        a2 += (double)x.z*(double)y.z; a3 += (double)x.w*(double)y.w;
    }
    double s = (a0+a1)+(a2+a3);
    #pragma unroll
    for (int o = 1; o < 8; o <<= 1) s += __shfl_xor(s, o, 64);
    if (ch == 0) g_Mp0[i*N+j] = s;
}

// m1 = Mp0 @ data2 ; m2 = Mp0^T @ data1 ; 2 threads per output (40 each)
__global__ void k_m12(const float* __restrict__ d1, const float* __restrict__ d2) {
    int gidx = blockIdx.x*256 + threadIdx.x;      // 163840 threads
    int t = gidx >> 1, ch = gidx & 1;
    double a0=0,a1=0;
    if (t < N*D) {
        int i = t / D, k = t % D;
        int j0 = ch*40;
        for (int j = j0; j < j0+40; j += 2) {
            a0 += g_Mp0[i*N+j]   * (double)d2[j*D+k];
            a1 += g_Mp0[i*N+j+1] * (double)d2[(j+1)*D+k];
        }
        double s = a0+a1; s += __shfl_xor(s, 1, 64);
        if (ch == 0) g_m[0][t] = s;
    } else {
        int r = t - N*D; int j = r / D, k = r % D;
        int i0 = ch*40;
        for (int i = i0; i < i0+40; i += 2) {
            a0 += g_Mp0[i*N+j]     * (double)d1[i*D+k];
            a1 += g_Mp0[(i+1)*N+j] * (double)d1[(i+1)*D+k];
        }
        double s = a0+a1; s += __shfl_xor(s, 1, 64);
        if (ch == 0) g_m[1][r] = s;
    }
}

// fused lam + u:  block per (g,row).  lam = ||data_row||/||m_row||; u = data + lam*m
__global__ void k_lamu(const float* __restrict__ d1, const float* __restrict__ d2) {
    __shared__ double red[512];
    int bid = blockIdx.x;          // 0..159
    int g = bid / N, row = bid % N;
    const float* dd = (g ? d2 : d1) + (size_t)row*D;
    const double* mm = g_m[g] + (size_t)row*D;
    int tid = threadIdx.x;
    double sd = 0.0, sm = 0.0;
    for (int c = tid; c < D; c += 256) {
        double a = (double)dd[c]; sd += a*a;
        double m = mm[c];         sm += m*m;
    }
    red[tid] = sd; red[256+tid] = sm; __syncthreads();
    for (int o = 128; o > 0; o >>= 1) {
        if (tid < o) { red[tid] += red[tid+o]; red[256+tid] += red[256+tid+o]; }
        __syncthreads();
    }
    double lam = sqrt(red[0]) / sqrt(red[256]);
    double* uu = g_u[g] + (size_t)row*D;
    for (int c = tid; c < D; c += 256) uu[c] = (double)dd[c] + lam*mm[c];
}

// fused e = l2norm_rows(relu(u @ W^T + b)) : block per (g,i), 512 threads.
// Each PAIR of threads (ch=0/1) computes TWO columns: kk and kk+256,
// each thread doing a 256-elem chunk (4 chains of 64), pair-combined by shfl.
__global__ void __launch_bounds__(512,1) k_e(const float* __restrict__ W, const float* __restrict__ b) {
    __shared__ double su[D];
    __shared__ double red[512];
    int bid = blockIdx.x;          // 0..159
    int g = bid / N, i = bid % N;
    int tid = threadIdx.x;
    const double* uu = g_u[g] + (size_t)i*D;
    su[tid] = uu[tid];
    __syncthreads();

    int kk = tid >> 1, ch = tid & 1;       // kk in [0,256)
    const double* sub = su + ch*256;
    double s0, s1;
    {
        const float4* Wr = reinterpret_cast<const float4*>(W + (size_t)kk*D + ch*256);
        double a0=0,a1=0,a2=0,a3=0;
        #pragma unroll
        for (int c4 = 0; c4 < 64; ++c4) {
            float4 w = Wr[c4];
            a0 += sub[4*c4+0]*(double)w.x; a1 += sub[4*c4+1]*(double)w.y;
            a2 += sub[4*c4+2]*(double)w.z; a3 += sub[4*c4+3]*(double)w.w;
        }
        s0 = (a0+a1)+(a2+a3);
    }
    {
        const float4* Wr = reinterpret_cast<const float4*>(W + (size_t)(kk+256)*D + ch*256);
        double a0=0,a1=0,a2=0,a3=0;
        #pragma unroll
        for (int c4 = 0; c4 < 64; ++c4) {
            float4 w = Wr[c4];
            a0 += sub[4*c4+0]*(double)w.x; a1 += sub[4*c4+1]*(double)w.y;
            a2 += sub[4*c4+2]*(double)w.z; a3 += sub[4*c4+3]*(double)w.w;
        }
        s1 = (a0+a1)+(a2+a3);
    }
    s0 += __shfl_xor(s0, 1, 64);
    s1 += __shfl_xor(s1, 1, 64);
    double acc0 = (double)b[kk]     + s0;
    double acc1 = (double)b[kk+256] + s1;
    double e0 = acc0 > 0.0 ? acc0 : 0.0;
    double e1 = acc1 > 0.0 ? acc1 : 0.0;

    red[tid] = (ch == 0) ? (e0*e0 + e1*e1) : 0.0; __syncthreads();
    for (int o = 256; o > 0; o >>= 1) { if (tid < o) red[tid] += red[tid+o]; __syncthreads(); }
    double nrm = sqrt(red[0]); if (nrm < 1e-12) nrm = 1e-12;
    double inv = 1.0 / nrm;
    if (ch == 0) {
        double* ee = g_e[g] + (size_t)i*D;
        ee[kk]       = e0*inv;
        ee[kk + 256] = e1*inv;
    }
}

// P[v] = e1n[i1] . e2n[i2] ; 8 threads per output, 64 doubles each
__global__ void k_p() {
    int gidx = blockIdx.x*256 + threadIdx.x;      // 51200 threads
    int v = gidx >> 3, ch = gidx & 7;
    int i1 = v % N, i2 = v / N;
    const double* a = g_e[0] + (size_t)i1*D + ch*64;
    const double* c2 = g_e[1] + (size_t)i2*D + ch*64;
    double a0=0,a1=0,a2=0,a3=0;
    #pragma unroll
    for (int c = 0; c < 64; c += 4) {
        a0 += a[c]*c2[c];     a1 += a[c+1]*c2[c+1];
        a2 += a[c+2]*c2[c+2]; a3 += a[c+3]*c2[c+3];
    }
    double s = (a0+a1)+(a2+a3);
    #pragma unroll
    for (int o = 1; o < 8; o <<= 1) s += __shfl_xor(s, o, 64);
    if (ch == 0) g_P[v] = s;
}

// 4-wave block reduction
__device__ __forceinline__ double bredux(double v, double* red4, double* sc, int slot, int tid) {
    #pragma unroll
    for (int o = 32; o > 0; o >>= 1) v += __shfl_down(v, o, 64);
    if ((tid & 63) == 0) red4[tid >> 6] = v;
    __syncthreads();
    if (tid == 0) sc[slot] = red4[0] + red4[1] + red4[2] + red4[3];
    __syncthreads();
    return sc[slot];
}

// Projected CG, reduced operator:
//   on null(A): PQPd = CQ*d - P(p.*d);   r0 = (6402/160) * P(p);  z = 1/80 + w.
__global__ void __launch_bounds__(256,1) k_pcg() {
    __shared__ double sd[NV];                 // search direction
    __shared__ double sq[NV];                 // y = p.*d, then q
    __shared__ double sRy[N], sCy[N];
    __shared__ double red4[4];
    __shared__ double sc[4];
    const double inv80 = 1.0/80.0, inv6400 = 1.0/6400.0, CHI = 1.0/80.0;
    int tid = threadIdx.x;
    double x[25], r[25], ploc[25];

    #pragma unroll
    for (int j = 0; j < 25; ++j) { int v = tid + 256*j; ploc[j] = g_P[v]; sq[v] = ploc[j]; }
    __syncthreads();

    // ---- setup: sums of p -> r0 = (6402/160) P(p) ----
    if (tid < N) {
        double cs = 0.0; const double* dd = sq + tid*N;
        for (int i1 = 0; i1 < N; ++i1) cs += dd[i1];
        sCy[tid] = cs;
    } else if (tid < 2*N) {
        int i1 = tid - N; double rr = 0.0;
        for (int i2 = 0; i2 < N; ++i2) rr += sq[i2*N + i1];
        sRy[i1] = rr;
    }
    __syncthreads();
    if (tid == 0) { double s = 0.0; for (int i = 0; i < N; ++i) s += sCy[i]; sc[0] = s; }
    __syncthreads();
    double Tp = sc[0];
    const double SCALE = 6402.0/160.0;
    double rsp = 0.0;
    #pragma unroll
    for (int j = 0; j < 25; ++j) {
        int v = tid + 256*j; int i1 = v % N, i2 = v / N;
        double rv = SCALE*(ploc[j] - sRy[i1]*inv80 - sCy[i2]*inv80 + Tp*inv6400);
        r[j] = rv; x[j] = 0.0; sd[v] = rv;
        rsp += rv*rv;
    }
    double rs = bredux(rsp, red4, sc, 2, tid);
    double rs0 = rs;

    // ---- main loop: q = CQ*d - P(p.*d) ----
    for (int it = 0; it < CG_MAX && rs > 1e-22*rs0; ++it) {
        #pragma unroll
        for (int j = 0; j < 25; ++j) { int v = tid + 256*j; sq[v] = ploc[j]*sd[v]; }
        __syncthreads();
        if (tid < N) {
            double cs = 0.0; const double* dd = sq + tid*N;
            for (int i1 = 0; i1 < N; ++i1) cs += dd[i1];
            sCy[tid] = cs;
        } else if (tid < 2*N) {
            int i1 = tid - N; double rr = 0.0;
            for (int i2 = 0; i2 < N; ++i2) rr += sq[i2*N + i1];
            sRy[i1] = rr;
        }
        __syncthreads();
        if (tid == 0) { double s = 0.0; for (int i = 0; i < N; ++i) s += sCy[i]; sc[1] = s; }
        __syncthreads();
        double Ty = sc[1];

        double dqp = 0.0;
        #pragma unroll
        for (int j = 0; j < 25; ++j) {
            int v = tid + 256*j; int i1 = v % N, i2 = v / N;
            double qv = CQ*sd[v] - (sq[v] - sRy[i1]*inv80 - sCy[i2]*inv80 + Ty*inv6400);
            sq[v] = qv;
            dqp += sd[v]*qv;
        }
        double dq = bredux(dqp, red4, sc, 3, tid);
        double alpha = rs / dq;

        double rsnp = 0.0;
        #pragma unroll
        for (int j = 0; j < 25; ++j) {
            int v = tid + 256*j;
            x[j] += alpha*sd[v];
            r[j] -= alpha*sq[v];
            rsnp += r[j]*r[j];
        }
        double rsn = bredux(rsnp, red4, sc, 2, tid);
        double beta = rsn / rs;
        rs = rsn;

        #pragma unroll
        for (int j = 0; j < 25; ++j) { int v = tid + 256*j; sd[v] = r[j] + beta*sd[v]; }
        __syncthreads();
    }

    #pragma unroll
    for (int j = 0; j < 25; ++j) { int v = tid + 256*j; g_z[v] = CHI + x[j]; }
}

// s = clip(z) ; out = softmax(1000*s, axis=i2)
__global__ void k_out(float* __restrict__ out) {
    __shared__ double red[128];
    int i1 = blockIdx.x, tid = threadIdx.x;
    double sv = 0.0, val = -1e300;
    if (tid < N) {
        sv = g_z[tid*N + i1];
        sv = sv < 0.0 ? 0.0 : (sv > 1.0 ? 1.0 : sv);
        val = sv;
    }
    red[tid] = val; __syncthreads();
    for (int o = 64; o > 0; o >>= 1) { if (tid < o) red[tid] = fmax(red[tid], red[tid+o]); __syncthreads(); }
    double m = red[0];
    __syncthreads();
    double w = 0.0;
    if (tid < N) w = exp(1000.0*(sv - m));
    red[tid] = w; __syncthreads();
    for (int o = 64; o > 0; o >>= 1) { if (tid < o) red[tid] += red[tid+o]; __syncthreads(); }
    double tot = red[0];
    if (tid < N) out[i1*N + tid] = (float)(w / tot);
}

extern "C" void kernel_launch(void* const* d_in, const int* in_sizes, int n_in,
                              void* d_out, int out_size, void* d_ws, size_t ws_size,
                              hipStream_t stream) {
    const float* d1 = (const float*)d_in[0];
    const float* d2 = (const float*)d_in[1];
    const float* W  = (const float*)d_in[2];
    const float* b  = (const float*)d_in[3];
    float* out = (float*)d_out;

    k_mp0 <<<dim3(200), dim3(256), 0, stream>>>(d1, d2);
    k_m12 <<<dim3(640), dim3(256), 0, stream>>>(d1, d2);
    k_lamu<<<dim3(160), dim3(256), 0, stream>>>(d1, d2);
    k_e   <<<dim3(160), dim3(512), 0, stream>>>(W, b);
    k_p   <<<dim3(200), dim3(256), 0, stream>>>();
    k_pcg <<<dim3(1),   dim3(256), 0, stream>>>();
    k_out <<<dim3(N),   dim3(128), 0, stream>>>(out);
}

// Round 9
// 76.157 us; speedup vs baseline: 36.6641x; 1.3970x over previous
//
#include <hip/hip_runtime.h>
#include <math.h>

#define N 80
#define D 512
#define NV (N*N)        // 6400
#define CQ 6241.000001  // (n1-1)*(n2-1) + ridge
#define CG_MAX 16

// ---- static device scratch ----
__device__ double g_Mp0[N*N];
__device__ double g_m[2][N*D];
__device__ double g_u[2][N*D];
__device__ double g_e[2][N*D];      // unnormalized relu(uW^T+b)
__device__ double g_in[2][N];       // 1/row-norm
__device__ float  g_WT[D*D];        // W transposed
__device__ double g_P[NV];          // p[v], v = i2*80 + i1
__device__ double g_z[NV];

// WT[c][k] = W[k][c]  (LDS 32x32 tiles, +1 pad)
__global__ void k_wt(const float* __restrict__ W) {
    __shared__ float t[32][33];
    int c0 = blockIdx.x*32, k0 = blockIdx.y*32;
    int tx = threadIdx.x, ty = threadIdx.y;     // 32 x 8
    #pragma unroll
    for (int j = 0; j < 4; ++j) t[ty+8*j][tx] = W[(size_t)(k0+ty+8*j)*D + c0+tx];
    __syncthreads();
    #pragma unroll
    for (int j = 0; j < 4; ++j) g_WT[(size_t)(c0+ty+8*j)*D + k0+tx] = t[tx][ty+8*j];
}

// Mp0 = data1 @ data2^T ; 8 threads per output, float4-interleaved chunks
__global__ void k_mp0(const float* __restrict__ d1, const float* __restrict__ d2) {
    int gidx = blockIdx.x*256 + threadIdx.x;      // 51200 threads
    int v = gidx >> 3, ch = gidx & 7;
    int i = v / N, j = v % N;
    const float4* A = reinterpret_cast<const float4*>(d1 + (size_t)i*D);
    const float4* B = reinterpret_cast<const float4*>(d2 + (size_t)j*D);
    double a0=0,a1=0,a2=0,a3=0;
    #pragma unroll
    for (int t = 0; t < 16; ++t) {
        float4 x = A[ch + 8*t], y = B[ch + 8*t];
        a0 += (double)x.x*(double)y.x; a1 += (double)x.y*(double)y.y;
        a2 += (double)x.z*(double)y.z; a3 += (double)x.w*(double)y.w;
    }
    double s = (a0+a1)+(a2+a3);
    #pragma unroll
    for (int o = 1; o < 8; o <<= 1) s += __shfl_xor(s, o, 64);
    if (ch == 0) g_Mp0[i*N+j] = s;
}

// m1 = Mp0 @ data2 ; m2 = Mp0^T @ data1 ; 2 threads per output (40 each)
__global__ void k_m12(const float* __restrict__ d1, const float* __restrict__ d2) {
    int gidx = blockIdx.x*256 + threadIdx.x;      // 163840 threads
    int t = gidx >> 1, ch = gidx & 1;
    double a0=0,a1=0;
    if (t < N*D) {
        int i = t / D, k = t % D;
        int j0 = ch*40;
        for (int j = j0; j < j0+40; j += 2) {
            a0 += g_Mp0[i*N+j]   * (double)d2[j*D+k];
            a1 += g_Mp0[i*N+j+1] * (double)d2[(j+1)*D+k];
        }
        double s = a0+a1; s += __shfl_xor(s, 1, 64);
        if (ch == 0) g_m[0][t] = s;
    } else {
        int r = t - N*D; int j = r / D, k = r % D;
        int i0 = ch*40;
        for (int i = i0; i < i0+40; i += 2) {
            a0 += g_Mp0[i*N+j]     * (double)d1[i*D+k];
            a1 += g_Mp0[(i+1)*N+j] * (double)d1[(i+1)*D+k];
        }
        double s = a0+a1; s += __shfl_xor(s, 1, 64);
        if (ch == 0) g_m[1][r] = s;
    }
}

// fused lam + u:  block per (g,row).  lam = ||data_row||/||m_row||; u = data + lam*m
__global__ void k_lamu(const float* __restrict__ d1, const float* __restrict__ d2) {
    __shared__ double red[512];
    int bid = blockIdx.x;          // 0..159
    int g = bid / N, row = bid % N;
    const float* dd = (g ? d2 : d1) + (size_t)row*D;
    const double* mm = g_m[g] + (size_t)row*D;
    int tid = threadIdx.x;
    double sd = 0.0, sm = 0.0;
    for (int c = tid; c < D; c += 256) {
        double a = (double)dd[c]; sd += a*a;
        double m = mm[c];         sm += m*m;
    }
    red[tid] = sd; red[256+tid] = sm; __syncthreads();
    for (int o = 128; o > 0; o >>= 1) {
        if (tid < o) { red[tid] += red[tid+o]; red[256+tid] += red[256+tid+o]; }
        __syncthreads();
    }
    double lam = sqrt(red[0]) / sqrt(red[256]);
    double* uu = g_u[g] + (size_t)row*D;
    for (int c = tid; c < D; c += 256) uu[c] = (double)dd[c] + lam*mm[c];
}

// e_raw = relu(u @ W^T + b) via WT: block = (row i, 128-col chunk), split-K=2.
// kk = tid&127, ch = tid>>7 -> lanes have consecutive k: coalesced WT loads,
// su[c] uniform-address broadcast (no LDS conflicts).
__global__ void __launch_bounds__(256,1) k_e(const float* __restrict__ b) {
    __shared__ double su[D];
    __shared__ double red[256];
    int bid = blockIdx.x;              // 0..639
    int ii = bid >> 2, chunk = bid & 3;
    int g = ii / N, i = ii % N;
    int k0 = chunk*128;
    int tid = threadIdx.x;
    const double* uu = g_u[g] + (size_t)i*D;
    su[tid] = uu[tid]; su[tid+256] = uu[tid+256];
    __syncthreads();

    int kk = tid & 127, ch = tid >> 7;
    int k = k0 + kk;
    int cbase = ch*256;
    double a0=0,a1=0,a2=0,a3=0,a4=0,a5=0,a6=0,a7=0;
    const float* wt = g_WT + k;
    #pragma unroll 4
    for (int t = 0; t < 32; ++t) {
        int c = cbase + t*8;
        a0 += su[c+0]*(double)wt[(size_t)(c+0)*D];
        a1 += su[c+1]*(double)wt[(size_t)(c+1)*D];
        a2 += su[c+2]*(double)wt[(size_t)(c+2)*D];
        a3 += su[c+3]*(double)wt[(size_t)(c+3)*D];
        a4 += su[c+4]*(double)wt[(size_t)(c+4)*D];
        a5 += su[c+5]*(double)wt[(size_t)(c+5)*D];
        a6 += su[c+6]*(double)wt[(size_t)(c+6)*D];
        a7 += su[c+7]*(double)wt[(size_t)(c+7)*D];
    }
    red[tid] = ((a0+a1)+(a2+a3)) + ((a4+a5)+(a6+a7));
    __syncthreads();
    if (tid < 128) {
        double acc = (double)b[k] + red[tid] + red[tid+128];
        g_e[g][(size_t)i*D + k] = acc > 0.0 ? acc : 0.0;
    }
}

// per-row inverse norms of e_raw
__global__ void k_nrm() {
    __shared__ double red[256];
    int bid = blockIdx.x;          // 0..159
    int g = bid / N, i = bid % N;
    int tid = threadIdx.x;
    const double* ee = g_e[g] + (size_t)i*D;
    double v1 = ee[tid], v2 = ee[tid+256];
    red[tid] = v1*v1 + v2*v2; __syncthreads();
    for (int o = 128; o > 0; o >>= 1) { if (tid < o) red[tid] += red[tid+o]; __syncthreads(); }
    if (tid == 0) {
        double nrm = sqrt(red[0]); if (nrm < 1e-12) nrm = 1e-12;
        g_in[g][i] = 1.0 / nrm;
    }
}

// P[v] = (e1[i1].e2[i2]) * in1[i1] * in2[i2] ; 8 threads/output, double2-interleaved
__global__ void k_p() {
    int gidx = blockIdx.x*256 + threadIdx.x;      // 51200 threads
    int v = gidx >> 3, ch = gidx & 7;
    int i1 = v % N, i2 = v / N;
    const double2* a = reinterpret_cast<const double2*>(g_e[0] + (size_t)i1*D);
    const double2* c2 = reinterpret_cast<const double2*>(g_e[1] + (size_t)i2*D);
    double a0=0,a1=0;
    #pragma unroll
    for (int t = 0; t < 32; ++t) {
        double2 x = a[ch + 8*t], y = c2[ch + 8*t];
        a0 += x.x*y.x; a1 += x.y*y.y;
    }
    double s = a0+a1;
    #pragma unroll
    for (int o = 1; o < 8; o <<= 1) s += __shfl_xor(s, o, 64);
    if (ch == 0) g_P[v] = s * g_in[0][i1] * g_in[1][i2];
}

// 4-wave block reduction
__device__ __forceinline__ double bredux(double v, double* red4, double* sc, int slot, int tid) {
    #pragma unroll
    for (int o = 32; o > 0; o >>= 1) v += __shfl_down(v, o, 64);
    if ((tid & 63) == 0) red4[tid >> 6] = v;
    __syncthreads();
    if (tid == 0) sc[slot] = red4[0] + red4[1] + red4[2] + red4[3];
    __syncthreads();
    return sc[slot];
}

// Projected CG, reduced operator:
//   on null(A): PQPd = CQ*d - P(p.*d);   r0 = (6402/160) * P(p);  z = 1/80 + w.
__global__ void __launch_bounds__(256,1) k_pcg() {
    __shared__ double sd[NV];                 // search direction
    __shared__ double sq[NV];                 // y = p.*d, then q
    __shared__ double sRy[N], sCy[N];
    __shared__ double red4[4];
    __shared__ double sc[4];
    const double inv80 = 1.0/80.0, inv6400 = 1.0/6400.0, CHI = 1.0/80.0;
    int tid = threadIdx.x;
    double x[25], r[25], ploc[25];

    #pragma unroll
    for (int j = 0; j < 25; ++j) { int v = tid + 256*j; ploc[j] = g_P[v]; sq[v] = ploc[j]; }
    __syncthreads();

    // ---- setup: sums of p -> r0 = (6402/160) P(p) ----
    if (tid < N) {
        double cs = 0.0; const double* dd = sq + tid*N;
        for (int i1 = 0; i1 < N; ++i1) cs += dd[i1];
        sCy[tid] = cs;
    } else if (tid < 2*N) {
        int i1 = tid - N; double rr = 0.0;
        for (int i2 = 0; i2 < N; ++i2) rr += sq[i2*N + i1];
        sRy[i1] = rr;
    }
    __syncthreads();
    if (tid == 0) { double s = 0.0; for (int i = 0; i < N; ++i) s += sCy[i]; sc[0] = s; }
    __syncthreads();
    double Tp = sc[0];
    const double SCALE = 6402.0/160.0;
    double rsp = 0.0;
    #pragma unroll
    for (int j = 0; j < 25; ++j) {
        int v = tid + 256*j; int i1 = v % N, i2 = v / N;
        double rv = SCALE*(ploc[j] - sRy[i1]*inv80 - sCy[i2]*inv80 + Tp*inv6400);
        r[j] = rv; x[j] = 0.0; sd[v] = rv;
        rsp += rv*rv;
    }
    double rs = bredux(rsp, red4, sc, 2, tid);
    double rs0 = rs;

    // ---- main loop: q = CQ*d - P(p.*d) ----
    for (int it = 0; it < CG_MAX && rs > 1e-22*rs0; ++it) {
        #pragma unroll
        for (int j = 0; j < 25; ++j) { int v = tid + 256*j; sq[v] = ploc[j]*sd[v]; }
        __syncthreads();
        if (tid < N) {
            double cs = 0.0; const double* dd = sq + tid*N;
            for (int i1 = 0; i1 < N; ++i1) cs += dd[i1];
            sCy[tid] = cs;
        } else if (tid < 2*N) {
            int i1 = tid - N; double rr = 0.0;
            for (int i2 = 0; i2 < N; ++i2) rr += sq[i2*N + i1];
            sRy[i1] = rr;
        }
        __syncthreads();
        if (tid == 0) { double s = 0.0; for (int i = 0; i < N; ++i) s += sCy[i]; sc[1] = s; }
        __syncthreads();
        double Ty = sc[1];

        double dqp = 0.0;
        #pragma unroll
        for (int j = 0; j < 25; ++j) {
            int v = tid + 256*j; int i1 = v % N, i2 = v / N;
            double qv = CQ*sd[v] - (sq[v] - sRy[i1]*inv80 - sCy[i2]*inv80 + Ty*inv6400);
            sq[v] = qv;
            dqp += sd[v]*qv;
        }
        double dq = bredux(dqp, red4, sc, 3, tid);
        double alpha = rs / dq;

        double rsnp = 0.0;
        #pragma unroll
        for (int j = 0; j < 25; ++j) {
            int v = tid + 256*j;
            x[j] += alpha*sd[v];
            r[j] -= alpha*sq[v];
            rsnp += r[j]*r[j];
        }
        double rsn = bredux(rsnp, red4, sc, 2, tid);
        double beta = rsn / rs;
        rs = rsn;

        #pragma unroll
        for (int j = 0; j < 25; ++j) { int v = tid + 256*j; sd[v] = r[j] + beta*sd[v]; }
        __syncthreads();
    }

    #pragma unroll
    for (int j = 0; j < 25; ++j) { int v = tid + 256*j; g_z[v] = CHI + x[j]; }
}

// s = clip(z) ; out = softmax(1000*s, axis=i2)
__global__ void k_out(float* __restrict__ out) {
    __shared__ double red[128];
    int i1 = blockIdx.x, tid = threadIdx.x;
    double sv = 0.0, val = -1e300;
    if (tid < N) {
        sv = g_z[tid*N + i1];
        sv = sv < 0.0 ? 0.0 : (sv > 1.0 ? 1.0 : sv);
        val = sv;
    }
    red[tid] = val; __syncthreads();
    for (int o = 64; o > 0; o >>= 1) { if (tid < o) red[tid] = fmax(red[tid], red[tid+o]); __syncthreads(); }
    double m = red[0];
    __syncthreads();
    double w = 0.0;
    if (tid < N) w = exp(1000.0*(sv - m));
    red[tid] = w; __syncthreads();
    for (int o = 64; o > 0; o >>= 1) { if (tid < o) red[tid] += red[tid+o]; __syncthreads(); }
    double tot = red[0];
    if (tid < N) out[i1*N + tid] = (float)(w / tot);
}

extern "C" void kernel_launch(void* const* d_in, const int* in_sizes, int n_in,
                              void* d_out, int out_size, void* d_ws, size_t ws_size,
                              hipStream_t stream) {
    const float* d1 = (const float*)d_in[0];
    const float* d2 = (const float*)d_in[1];
    const float* W  = (const float*)d_in[2];
    const float* b  = (const float*)d_in[3];
    float* out = (float*)d_out;

    k_wt  <<<dim3(16,16), dim3(32,8), 0, stream>>>(W);
    k_mp0 <<<dim3(200), dim3(256), 0, stream>>>(d1, d2);
    k_m12 <<<dim3(640), dim3(256), 0, stream>>>(d1, d2);
    k_lamu<<<dim3(160), dim3(256), 0, stream>>>(d1, d2);
    k_e   <<<dim3(640), dim3(256), 0, stream>>>(b);
    k_nrm <<<dim3(160), dim3(256), 0, stream>>>();
    k_p   <<<dim3(200), dim3(256), 0, stream>>>();
    k_pcg <<<dim3(1),   dim3(256), 0, stream>>>();
    k_out <<<dim3(N),   dim3(128), 0, stream>>>(out);
}

// Round 10
// 70.130 us; speedup vs baseline: 39.8152x; 1.0859x over previous
//
#include <hip/hip_runtime.h>
#include <math.h>

#define N 80
#define D 512
#define NV (N*N)        // 6400
#define CQ 6241.000001  // (n1-1)*(n2-1) + ridge
#define CG_MAX 16

// ---- static device scratch ----
__device__ double g_Mp0[N*N];
__device__ float  g_WT[D*D];        // W transposed
__device__ double g_e[2][N*D];      // normalized embeddings
__device__ double g_P[NV];          // p[v], v = i2*80 + i1

// k_pre: blocks 0..255 transpose W into WT (32x32 LDS tiles);
//        blocks 256..455 compute Mp0 = d1 @ d2^T (8 threads/output).
__global__ void k_pre(const float* __restrict__ W,
                      const float* __restrict__ d1, const float* __restrict__ d2) {
    int bid = blockIdx.x;
    int tid = threadIdx.x;
    if (bid < 256) {
        __shared__ float t[32][33];
        int c0 = (bid & 15)*32, k0 = (bid >> 4)*32;
        int tx = tid & 31, ty = tid >> 5;       // 32 x 8
        #pragma unroll
        for (int j = 0; j < 4; ++j) t[ty+8*j][tx] = W[(size_t)(k0+ty+8*j)*D + c0+tx];
        __syncthreads();
        #pragma unroll
        for (int j = 0; j < 4; ++j) g_WT[(size_t)(c0+ty+8*j)*D + k0+tx] = t[tx][ty+8*j];
    } else {
        int gidx = (bid-256)*256 + tid;         // 51200 threads
        int v = gidx >> 3, ch = gidx & 7;
        int i = v / N, j = v % N;
        const float4* A = reinterpret_cast<const float4*>(d1 + (size_t)i*D);
        const float4* B = reinterpret_cast<const float4*>(d2 + (size_t)j*D);
        double a0=0,a1=0,a2=0,a3=0;
        #pragma unroll
        for (int t = 0; t < 16; ++t) {
            float4 x = A[ch + 8*t], y = B[ch + 8*t];
            a0 += (double)x.x*(double)y.x; a1 += (double)x.y*(double)y.y;
            a2 += (double)x.z*(double)y.z; a3 += (double)x.w*(double)y.w;
        }
        double s = (a0+a1)+(a2+a3);
        #pragma unroll
        for (int o = 1; o < 8; o <<= 1) s += __shfl_xor(s, o, 64);
        if (ch == 0) g_Mp0[i*N+j] = s;
    }
}

// k_mue: fused m-row -> lam -> u -> e-row -> row-normalize.
// One block per (g,row), 512 threads, thread k owns output column k.
//  g=0: m1[row,k] = sum_j Mp0[row,j]*d2[j,k];  data row = d1[row]
//  g=1: m2[row,k] = sum_i Mp0[i,row]*d1[i,k];  data row = d2[row]
__global__ void __launch_bounds__(512,1) k_mue(const float* __restrict__ d1,
                                               const float* __restrict__ d2,
                                               const float* __restrict__ b) {
    __shared__ double mp[N];
    __shared__ double su[D];
    __shared__ double red[512];
    __shared__ double red2[512];
    int bid = blockIdx.x;          // 0..159
    int g = bid / N, row = bid % N;
    int tid = threadIdx.x;         // = k
    const float* dsrc = g ? d1 : d2;    // summed rows for m
    const float* dme  = g ? d2 : d1;    // own data row

    if (tid < N) mp[tid] = g ? g_Mp0[tid*N + row] : g_Mp0[row*N + tid];
    __syncthreads();

    // m_k
    double m0=0,m1=0,m2=0,m3=0;
    #pragma unroll 4
    for (int j = 0; j < N; j += 4) {
        m0 += mp[j]   * (double)dsrc[(size_t)j*D     + tid];
        m1 += mp[j+1] * (double)dsrc[(size_t)(j+1)*D + tid];
        m2 += mp[j+2] * (double)dsrc[(size_t)(j+2)*D + tid];
        m3 += mp[j+3] * (double)dsrc[(size_t)(j+3)*D + tid];
    }
    double mk = (m0+m1)+(m2+m3);
    double ak = (double)dme[(size_t)row*D + tid];

    // lam = ||a|| / ||m||
    red[tid] = ak*ak; red2[tid] = mk*mk; __syncthreads();
    for (int o = 256; o > 0; o >>= 1) {
        if (tid < o) { red[tid] += red[tid+o]; red2[tid] += red2[tid+o]; }
        __syncthreads();
    }
    double lam = sqrt(red[0]) / sqrt(red2[0]);
    __syncthreads();

    // u into LDS
    su[tid] = ak + lam*mk;
    __syncthreads();

    // e_k = relu(b_k + sum_c su[c]*WT[c][k])   (8 chains, coalesced WT)
    const float* wt = g_WT + tid;
    double a0=0,a1=0,a2=0,a3=0,a4=0,a5=0,a6=0,a7=0;
    #pragma unroll 8
    for (int t = 0; t < 64; ++t) {
        int c = t*8;
        a0 += su[c+0]*(double)wt[(size_t)(c+0)*D];
        a1 += su[c+1]*(double)wt[(size_t)(c+1)*D];
        a2 += su[c+2]*(double)wt[(size_t)(c+2)*D];
        a3 += su[c+3]*(double)wt[(size_t)(c+3)*D];
        a4 += su[c+4]*(double)wt[(size_t)(c+4)*D];
        a5 += su[c+5]*(double)wt[(size_t)(c+5)*D];
        a6 += su[c+6]*(double)wt[(size_t)(c+6)*D];
        a7 += su[c+7]*(double)wt[(size_t)(c+7)*D];
    }
    double acc = (double)b[tid] + ((a0+a1)+(a2+a3)) + ((a4+a5)+(a6+a7));
    double ek = acc > 0.0 ? acc : 0.0;

    // row normalize
    red[tid] = ek*ek; __syncthreads();
    for (int o = 256; o > 0; o >>= 1) { if (tid < o) red[tid] += red[tid+o]; __syncthreads(); }
    double nrm = sqrt(red[0]); if (nrm < 1e-12) nrm = 1e-12;
    g_e[g][(size_t)row*D + tid] = ek / nrm;
}

// P[v] = e1n[i1] . e2n[i2] ; 8 threads/output, double2-interleaved
__global__ void k_p() {
    int gidx = blockIdx.x*256 + threadIdx.x;      // 51200 threads
    int v = gidx >> 3, ch = gidx & 7;
    int i1 = v % N, i2 = v / N;
    const double2* a = reinterpret_cast<const double2*>(g_e[0] + (size_t)i1*D);
    const double2* c2 = reinterpret_cast<const double2*>(g_e[1] + (size_t)i2*D);
    double a0=0,a1=0;
    #pragma unroll
    for (int t = 0; t < 32; ++t) {
        double2 x = a[ch + 8*t], y = c2[ch + 8*t];
        a0 += x.x*y.x; a1 += x.y*y.y;
    }
    double s = a0+a1;
    #pragma unroll
    for (int o = 1; o < 8; o <<= 1) s += __shfl_xor(s, o, 64);
    if (ch == 0) g_P[v] = s;
}

// 4-wave block reduction
__device__ __forceinline__ double bredux(double v, double* red4, double* sc, int slot, int tid) {
    #pragma unroll
    for (int o = 32; o > 0; o >>= 1) v += __shfl_down(v, o, 64);
    if ((tid & 63) == 0) red4[tid >> 6] = v;
    __syncthreads();
    if (tid == 0) sc[slot] = red4[0] + red4[1] + red4[2] + red4[3];
    __syncthreads();
    return sc[slot];
}

// Projected CG + clip + softmax + output, single block.
//   on null(A): PQPd = CQ*d - P(p.*d);   r0 = (6402/160) * P(p);  z = 1/80 + w.
__global__ void __launch_bounds__(256,1) k_pcgout(float* __restrict__ out) {
    __shared__ double sd[NV];                 // search direction / exp scratch
    __shared__ double sq[NV];                 // y = p.*d, then q, then z
    __shared__ double sRy[N], sCy[N];
    __shared__ double red4[4];
    __shared__ double sc[4];
    const double inv80 = 1.0/80.0, inv6400 = 1.0/6400.0, CHI = 1.0/80.0;
    int tid = threadIdx.x;
    double x[25], r[25], ploc[25];

    #pragma unroll
    for (int j = 0; j < 25; ++j) { int v = tid + 256*j; ploc[j] = g_P[v]; sq[v] = ploc[j]; }
    __syncthreads();

    // ---- setup: sums of p -> r0 = (6402/160) P(p) ----
    if (tid < N) {
        double cs = 0.0; const double* dd = sq + tid*N;
        for (int i1 = 0; i1 < N; ++i1) cs += dd[i1];
        sCy[tid] = cs;
    } else if (tid < 2*N) {
        int i1 = tid - N; double rr = 0.0;
        for (int i2 = 0; i2 < N; ++i2) rr += sq[i2*N + i1];
        sRy[i1] = rr;
    }
    __syncthreads();
    if (tid == 0) { double s = 0.0; for (int i = 0; i < N; ++i) s += sCy[i]; sc[0] = s; }
    __syncthreads();
    double Tp = sc[0];
    const double SCALE = 6402.0/160.0;
    double rsp = 0.0;
    #pragma unroll
    for (int j = 0; j < 25; ++j) {
        int v = tid + 256*j; int i1 = v % N, i2 = v / N;
        double rv = SCALE*(ploc[j] - sRy[i1]*inv80 - sCy[i2]*inv80 + Tp*inv6400);
        r[j] = rv; x[j] = 0.0; sd[v] = rv;
        rsp += rv*rv;
    }
    double rs = bredux(rsp, red4, sc, 2, tid);
    double rs0 = rs;

    // ---- main loop: q = CQ*d - P(p.*d) ----
    for (int it = 0; it < CG_MAX && rs > 1e-22*rs0; ++it) {
        #pragma unroll
        for (int j = 0; j < 25; ++j) { int v = tid + 256*j; sq[v] = ploc[j]*sd[v]; }
        __syncthreads();
        if (tid < N) {
            double cs = 0.0; const double* dd = sq + tid*N;
            for (int i1 = 0; i1 < N; ++i1) cs += dd[i1];
            sCy[tid] = cs;
        } else if (tid < 2*N) {
            int i1 = tid - N; double rr = 0.0;
            for (int i2 = 0; i2 < N; ++i2) rr += sq[i2*N + i1];
            sRy[i1] = rr;
        }
        __syncthreads();
        if (tid == 0) { double s = 0.0; for (int i = 0; i < N; ++i) s += sCy[i]; sc[1] = s; }
        __syncthreads();
        double Ty = sc[1];

        double dqp = 0.0;
        #pragma unroll
        for (int j = 0; j < 25; ++j) {
            int v = tid + 256*j; int i1 = v % N, i2 = v / N;
            double qv = CQ*sd[v] - (sq[v] - sRy[i1]*inv80 - sCy[i2]*inv80 + Ty*inv6400);
            sq[v] = qv;
            dqp += sd[v]*qv;
        }
        double dq = bredux(dqp, red4, sc, 3, tid);
        double alpha = rs / dq;

        double rsnp = 0.0;
        #pragma unroll
        for (int j = 0; j < 25; ++j) {
            int v = tid + 256*j;
            x[j] += alpha*sd[v];
            r[j] -= alpha*sq[v];
            rsnp += r[j]*r[j];
        }
        double rsn = bredux(rsnp, red4, sc, 2, tid);
        double beta = rsn / rs;
        rs = rsn;

        #pragma unroll
        for (int j = 0; j < 25; ++j) { int v = tid + 256*j; sd[v] = r[j] + beta*sd[v]; }
        __syncthreads();
    }

    // ---- epilogue: z = clip(1/80 + x), softmax(1000*z) over i2 per column i1 ----
    #pragma unroll
    for (int j = 0; j < 25; ++j) {
        int v = tid + 256*j;
        double z = CHI + x[j];
        sq[v] = z < 0.0 ? 0.0 : (z > 1.0 ? 1.0 : z);
    }
    __syncthreads();
    if (tid < N) {
        int i1 = tid;
        double mx = -1e300;
        for (int i2 = 0; i2 < N; ++i2) mx = fmax(mx, sq[i2*N + i1]);
        double s = 0.0;
        for (int i2 = 0; i2 < N; ++i2) {
            double e = exp(1000.0*(sq[i2*N + i1] - mx));
            sd[i2*N + i1] = e; s += e;
        }
        double invs = 1.0 / s;
        for (int i2 = 0; i2 < N; ++i2) out[i1*N + i2] = (float)(sd[i2*N + i1] * invs);
    }
}

extern "C" void kernel_launch(void* const* d_in, const int* in_sizes, int n_in,
                              void* d_out, int out_size, void* d_ws, size_t ws_size,
                              hipStream_t stream) {
    const float* d1 = (const float*)d_in[0];
    const float* d2 = (const float*)d_in[1];
    const float* W  = (const float*)d_in[2];
    const float* b  = (const float*)d_in[3];
    float* out = (float*)d_out;

    k_pre   <<<dim3(456), dim3(256), 0, stream>>>(W, d1, d2);
    k_mue   <<<dim3(160), dim3(512), 0, stream>>>(d1, d2, b);
    k_p     <<<dim3(200), dim3(256), 0, stream>>>();
    k_pcgout<<<dim3(1),   dim3(256), 0, stream>>>(out);
}